// Round 2
// baseline (499.149 us; speedup 1.0000x reference)
//
#include <hip/hip_runtime.h>

#define N_NODES 100000
#define N_EDGES 1600000
#define D 32

// ---------------- degree accumulation (over dst), w >= 0 ----------------
__global__ void k_deg(const int* __restrict__ dst, const float* __restrict__ w,
                      float* __restrict__ deg) {
    int e = blockIdx.x * blockDim.x + threadIdx.x;
    if (e < N_EDGES) {
        int d = dst[e];
        if ((unsigned)d < N_NODES) atomicAdd(&deg[d], w[e]);
    }
}

// deg -> dis = rsqrt(deg + 1)   (+1 is the self-loop weight; always > 0)
__global__ void k_dis(float* __restrict__ deg) {
    int i = blockIdx.x * blockDim.x + threadIdx.x;
    if (i < N_NODES) {
        float dg = deg[i] + 1.0f;
        deg[i] = rsqrtf(dg);
    }
}

// coef[e] = dis[src] * w * dis[dst]   (self-loop coef handled in k_final)
__global__ void k_coef(const int* __restrict__ src, const int* __restrict__ dst,
                       const float* __restrict__ w, const float* __restrict__ dis,
                       float* __restrict__ coef) {
    int e = blockIdx.x * blockDim.x + threadIdx.x;
    if (e < N_EDGES) {
        int s = src[e], d = dst[e];
        float c = 0.f;
        if ((unsigned)s < N_NODES && (unsigned)d < N_NODES)
            c = dis[s] * w[e] * dis[d];
        coef[e] = c;
    }
}

// Y[n][j] = sum_k X[n][k] * W[k][j]    (X: [N,32], W: [32,32] row-major)
__global__ void k_gemm32(const float* __restrict__ X, const float* __restrict__ W,
                         float* __restrict__ Y) {
    __shared__ float Ws[D * D];
    __shared__ float Xs[8][D];
    int t = threadIdx.x;  // 256 threads = 8 nodes x 32 features
    for (int i = t; i < D * D; i += 256) Ws[i] = W[i];
    int local = t >> 5, j = t & 31;
    int node = blockIdx.x * 8 + local;
    if (node < N_NODES) Xs[local][j] = X[node * D + j];
    __syncthreads();
    if (node < N_NODES) {
        float acc = 0.f;
#pragma unroll
        for (int k = 0; k < D; ++k) acc = fmaf(Xs[local][k], Ws[k * D + j], acc);
        Y[node * D + j] = acc;
    }
}

// out[dst] += coef * xm[src], one thread per (edge, feature)
__global__ void k_scatter(const int* __restrict__ src, const int* __restrict__ dst,
                          const float* __restrict__ coef, const float* __restrict__ xm,
                          float* __restrict__ out) {
    long long gid = (long long)blockIdx.x * blockDim.x + threadIdx.x;
    if (gid >= (long long)N_EDGES * D) return;
    int e = (int)(gid >> 5);
    int f = (int)(gid & 31);
    int s = src[e], d = dst[e];
    if ((unsigned)s >= N_NODES || (unsigned)d >= N_NODES) return;
    float c = coef[e];
    atomicAdd(&out[d * D + f], c * xm[s * D + f]);
}

// acc = [relu]( acc + dis[i]^2 * xm[i] + b )   (self-loop + bias + activation)
__global__ void k_final(float* __restrict__ acc, const float* __restrict__ xm,
                        const float* __restrict__ dis, const float* __restrict__ b,
                        int do_relu) {
    int gid = blockIdx.x * blockDim.x + threadIdx.x;
    if (gid < N_NODES * D) {
        int i = gid >> 5, f = gid & 31;
        float s = dis[i];
        float v = acc[gid] + s * s * xm[gid] + b[f];
        if (do_relu) v = fmaxf(v, 0.f);
        acc[gid] = v;
    }
}

extern "C" void kernel_launch(void* const* d_in, const int* in_sizes, int n_in,
                              void* d_out, int out_size, void* d_ws, size_t ws_size,
                              hipStream_t stream) {
    const float* x  = (const float*)d_in[0];
    const int*   ei = (const int*)d_in[1];   // [2, E] flat: row 0 = src, row 1 = dst
    const float* w  = (const float*)d_in[2];
    const float* W1 = (const float*)d_in[3];
    const float* b1 = (const float*)d_in[4];
    const float* W2 = (const float*)d_in[5];
    const float* b2 = (const float*)d_in[6];
    const int* src = ei;
    const int* dst = ei + N_EDGES;
    float* out = (float*)d_out;

    // workspace layout (floats): dis[N] | coef[E] | xm[N*D] | h[N*D]  (~33 MB)
    float* dis  = (float*)d_ws;
    float* coef = dis + N_NODES;
    float* xm   = coef + N_EDGES;
    float* h    = xm + (size_t)N_NODES * D;

    // ---- normalization coefficients (computed once, reused by both layers) ----
    hipMemsetAsync(dis, 0, N_NODES * sizeof(float), stream);
    k_deg<<<(N_EDGES + 255) / 256, 256, 0, stream>>>(dst, w, dis);
    k_dis<<<(N_NODES + 255) / 256, 256, 0, stream>>>(dis);
    k_coef<<<(N_EDGES + 255) / 256, 256, 0, stream>>>(src, dst, w, dis, coef);

    // ---- layer 1: h = relu(A_hat @ (x @ W1) + b1) ----
    k_gemm32<<<(N_NODES + 7) / 8, 256, 0, stream>>>(x, W1, xm);
    hipMemsetAsync(h, 0, (size_t)N_NODES * D * sizeof(float), stream);
    k_scatter<<<(N_EDGES * D + 255) / 256, 256, 0, stream>>>(src, dst, coef, xm, h);
    k_final<<<(N_NODES * D + 255) / 256, 256, 0, stream>>>(h, xm, dis, b1, 1);

    // ---- layer 2: out = A_hat @ (h @ W2) + b2 ----
    k_gemm32<<<(N_NODES + 7) / 8, 256, 0, stream>>>(h, W2, xm);
    hipMemsetAsync(out, 0, (size_t)out_size * sizeof(float), stream);
    k_scatter<<<(N_EDGES * D + 255) / 256, 256, 0, stream>>>(src, dst, coef, xm, out);
    k_final<<<(N_NODES * D + 255) / 256, 256, 0, stream>>>(out, xm, dis, b2, 0);
}

// Round 3
// 394.315 us; speedup vs baseline: 1.2659x; 1.2659x over previous
//
#include <hip/hip_runtime.h>

#define N_NODES 100000
#define N_EDGES 1600000
#define D 32
#define SCAN_BLK 1024
#define SCAN_NB ((N_NODES + SCAN_BLK - 1) / SCAN_BLK)   // 98

// ---------------------------------------------------------------- shared bits
// deg -> dis = rsqrt(deg + 1)   (+1 is the self-loop weight; always > 0)
__global__ void k_dis(float* __restrict__ deg) {
    int i = blockIdx.x * blockDim.x + threadIdx.x;
    if (i < N_NODES) deg[i] = rsqrtf(deg[i] + 1.0f);
}

// Y[n][j] = sum_k X[n][k] * W[k][j]    (X: [N,32], W: [32,32] row-major)
__global__ void k_gemm32(const float* __restrict__ X, const float* __restrict__ W,
                         float* __restrict__ Y) {
    __shared__ float Ws[D * D];
    __shared__ float Xs[8][D];
    int t = threadIdx.x;  // 256 threads = 8 nodes x 32 features
    for (int i = t; i < D * D; i += 256) Ws[i] = W[i];
    int local = t >> 5, j = t & 31;
    int node = blockIdx.x * 8 + local;
    if (node < N_NODES) Xs[local][j] = X[node * D + j];
    __syncthreads();
    if (node < N_NODES) {
        float acc = 0.f;
#pragma unroll
        for (int k = 0; k < D; ++k) acc = fmaf(Xs[local][k], Ws[k * D + j], acc);
        Y[node * D + j] = acc;
    }
}

// ------------------------------------------------------------- CSR build path
// histogram of dst (edge counts) + weighted degree, in one pass
__global__ void k_hist(const int* __restrict__ dst, const float* __restrict__ w,
                       float* __restrict__ deg, int* __restrict__ cnt) {
    int e = blockIdx.x * blockDim.x + threadIdx.x;
    if (e < N_EDGES) {
        int d = dst[e];
        if ((unsigned)d < N_NODES) {
            atomicAdd(&deg[d], w[e]);
            atomicAdd(&cnt[d], 1);
        }
    }
}

// per-block inclusive scan (Hillis-Steele) + block totals
__global__ void k_scan1(const int* __restrict__ cnt, int* __restrict__ incl,
                        int* __restrict__ bsum) {
    __shared__ int sh[SCAN_BLK];
    int t = threadIdx.x;
    int g = blockIdx.x * SCAN_BLK + t;
    int v = (g < N_NODES) ? cnt[g] : 0;
    sh[t] = v;
    __syncthreads();
    for (int off = 1; off < SCAN_BLK; off <<= 1) {
        int add = (t >= off) ? sh[t - off] : 0;
        __syncthreads();
        sh[t] += add;
        __syncthreads();
    }
    if (g < N_NODES) incl[g] = sh[t];
    if (t == SCAN_BLK - 1) bsum[blockIdx.x] = sh[t];
}

// single-block exclusive scan of the SCAN_NB block totals
__global__ void k_scan2(const int* __restrict__ bsum, int* __restrict__ boffs) {
    __shared__ int sh[256];
    int t = threadIdx.x;
    int v = (t < SCAN_NB) ? bsum[t] : 0;
    sh[t] = v;
    __syncthreads();
    for (int off = 1; off < 256; off <<= 1) {
        int add = (t >= off) ? sh[t - off] : 0;
        __syncthreads();
        sh[t] += add;
        __syncthreads();
    }
    if (t < SCAN_NB) boffs[t] = sh[t] - v;  // exclusive
}

// rowptr (exclusive) = incl - cnt + block offset
__global__ void k_scan3(const int* __restrict__ cnt, const int* __restrict__ incl,
                        const int* __restrict__ boffs, int* __restrict__ rowptr) {
    int g = blockIdx.x * 256 + threadIdx.x;
    if (g < N_NODES) rowptr[g] = incl[g] - cnt[g] + boffs[g / SCAN_BLK];
    if (g == 0) rowptr[N_NODES] = N_EDGES;
}

// drop each edge's {coef, src} into its dst's CSR segment
__global__ void k_fill(const int* __restrict__ src, const int* __restrict__ dst,
                       const float* __restrict__ w, const float* __restrict__ dis,
                       const int* __restrict__ rowptr, int* __restrict__ fill,
                       float2* __restrict__ edge2) {
    int e = blockIdx.x * blockDim.x + threadIdx.x;
    if (e >= N_EDGES) return;
    int s = src[e], d = dst[e];
    if ((unsigned)s >= N_NODES || (unsigned)d >= N_NODES) return;
    int pos = rowptr[d] + atomicAdd(&fill[d], 1);
    float c = dis[s] * w[e] * dis[d];
    edge2[pos] = make_float2(c, __int_as_float(s));
}

// out[n] = [relu]( sum_{e in CSR[n]} coef_e * xm[src_e] + dis[n]^2*xm[n] + b )
// 32 lanes per node (one feature each); 8 nodes per 256-thread block.
__global__ void k_gather(const int* __restrict__ rowptr, const float2* __restrict__ edge2,
                         const float* __restrict__ xm, const float* __restrict__ dis,
                         const float* __restrict__ b, float* __restrict__ out,
                         int do_relu) {
    int t = threadIdx.x;
    int node = blockIdx.x * 8 + (t >> 5);
    int f = t & 31;
    if (node >= N_NODES) return;
    int beg = rowptr[node], end = rowptr[node + 1];
    float acc0 = 0.f, acc1 = 0.f;
    int j = beg;
    for (; j + 1 < end; j += 2) {
        float2 e0 = edge2[j];
        float2 e1 = edge2[j + 1];
        acc0 = fmaf(e0.x, xm[(size_t)__float_as_int(e0.y) * D + f], acc0);
        acc1 = fmaf(e1.x, xm[(size_t)__float_as_int(e1.y) * D + f], acc1);
    }
    if (j < end) {
        float2 e0 = edge2[j];
        acc0 = fmaf(e0.x, xm[(size_t)__float_as_int(e0.y) * D + f], acc0);
    }
    float s = dis[node];
    float v = acc0 + acc1 + s * s * xm[(size_t)node * D + f] + b[f];
    if (do_relu) v = fmaxf(v, 0.f);
    out[(size_t)node * D + f] = v;
}

// ------------------------------------------------- fallback (round-2 atomics)
__global__ void k_coef(const int* __restrict__ src, const int* __restrict__ dst,
                       const float* __restrict__ w, const float* __restrict__ dis,
                       float* __restrict__ coef) {
    int e = blockIdx.x * blockDim.x + threadIdx.x;
    if (e < N_EDGES) {
        int s = src[e], d = dst[e];
        float c = 0.f;
        if ((unsigned)s < N_NODES && (unsigned)d < N_NODES)
            c = dis[s] * w[e] * dis[d];
        coef[e] = c;
    }
}

__global__ void k_scatter(const int* __restrict__ src, const int* __restrict__ dst,
                          const float* __restrict__ coef, const float* __restrict__ xm,
                          float* __restrict__ out) {
    long long gid = (long long)blockIdx.x * blockDim.x + threadIdx.x;
    if (gid >= (long long)N_EDGES * D) return;
    int e = (int)(gid >> 5);
    int f = (int)(gid & 31);
    int s = src[e], d = dst[e];
    if ((unsigned)s >= N_NODES || (unsigned)d >= N_NODES) return;
    atomicAdd(&out[d * D + f], coef[e] * xm[s * D + f]);
}

__global__ void k_final(float* __restrict__ acc, const float* __restrict__ xm,
                        const float* __restrict__ dis, const float* __restrict__ b,
                        int do_relu) {
    int gid = blockIdx.x * blockDim.x + threadIdx.x;
    if (gid < N_NODES * D) {
        int i = gid >> 5, f = gid & 31;
        float s = dis[i];
        float v = acc[gid] + s * s * xm[gid] + b[f];
        if (do_relu) v = fmaxf(v, 0.f);
        acc[gid] = v;
    }
}

extern "C" void kernel_launch(void* const* d_in, const int* in_sizes, int n_in,
                              void* d_out, int out_size, void* d_ws, size_t ws_size,
                              hipStream_t stream) {
    const float* x  = (const float*)d_in[0];
    const int*   ei = (const int*)d_in[1];   // [2, E] flat: row 0 = src, row 1 = dst
    const float* w  = (const float*)d_in[2];
    const float* W1 = (const float*)d_in[3];
    const float* b1 = (const float*)d_in[4];
    const float* W2 = (const float*)d_in[5];
    const float* b2 = (const float*)d_in[6];
    const int* src = ei;
    const int* dst = ei + N_EDGES;
    float* out = (float*)d_out;

    // ---- CSR-path workspace layout ----
    // dis[N] | cnt[N] | fill[N] | incl[N] | bsum[256] | boffs[256] |
    // rowptr[N+1 (+pad)] | edge2[E]*2 | xm[N*D] | h[N*D]
    char* p = (char*)d_ws;
    float* dis   = (float*)p;                 p += (size_t)N_NODES * 4;
    int*   cnt   = (int*)p;                   p += (size_t)N_NODES * 4;
    int*   fill  = (int*)p;                   p += (size_t)N_NODES * 4;
    int*   incl  = (int*)p;                   p += (size_t)N_NODES * 4;
    int*   bsum  = (int*)p;                   p += 256 * 4;
    int*   boffs = (int*)p;                   p += 256 * 4;
    int*   rowptr= (int*)p;                   p += (size_t)(N_NODES + 2) * 4; // +pad keeps 8B align
    float2* edge2= (float2*)p;                p += (size_t)N_EDGES * 8;
    float* xm    = (float*)p;                 p += (size_t)N_NODES * D * 4;
    float* h     = (float*)p;                 p += (size_t)N_NODES * D * 4;
    size_t need = (size_t)(p - (char*)d_ws);

    if (ws_size >= need) {
        // ---- CSR build ----
        hipMemsetAsync(dis, 0, N_NODES * sizeof(float), stream);
        hipMemsetAsync(cnt, 0, N_NODES * sizeof(int), stream);
        hipMemsetAsync(fill, 0, N_NODES * sizeof(int), stream);
        k_hist<<<(N_EDGES + 255) / 256, 256, 0, stream>>>(dst, w, dis, cnt);
        k_dis<<<(N_NODES + 255) / 256, 256, 0, stream>>>(dis);
        k_scan1<<<SCAN_NB, SCAN_BLK, 0, stream>>>(cnt, incl, bsum);
        k_scan2<<<1, 256, 0, stream>>>(bsum, boffs);
        k_scan3<<<(N_NODES + 255) / 256, 256, 0, stream>>>(cnt, incl, boffs, rowptr);
        k_fill<<<(N_EDGES + 255) / 256, 256, 0, stream>>>(src, dst, w, dis, rowptr, fill, edge2);

        // ---- layer 1: h = relu(A_hat @ (x @ W1) + b1) ----
        k_gemm32<<<(N_NODES + 7) / 8, 256, 0, stream>>>(x, W1, xm);
        k_gather<<<(N_NODES + 7) / 8, 256, 0, stream>>>(rowptr, edge2, xm, dis, b1, h, 1);

        // ---- layer 2: out = A_hat @ (h @ W2) + b2 ----
        k_gemm32<<<(N_NODES + 7) / 8, 256, 0, stream>>>(h, W2, xm);
        k_gather<<<(N_NODES + 7) / 8, 256, 0, stream>>>(rowptr, edge2, xm, dis, b2, out, 0);
    } else {
        // ---- fallback: round-2 atomic-scatter pipeline (ws >= ~33 MB) ----
        float* fdis  = (float*)d_ws;
        float* coef  = fdis + N_NODES;
        float* fxm   = coef + N_EDGES;
        float* fh    = fxm + (size_t)N_NODES * D;

        hipMemsetAsync(fdis, 0, N_NODES * sizeof(float), stream);
        k_hist<<<(N_EDGES + 255) / 256, 256, 0, stream>>>(dst, w, fdis, (int*)coef); // cnt unused scratch
        k_dis<<<(N_NODES + 255) / 256, 256, 0, stream>>>(fdis);
        k_coef<<<(N_EDGES + 255) / 256, 256, 0, stream>>>(src, dst, w, fdis, coef);

        k_gemm32<<<(N_NODES + 7) / 8, 256, 0, stream>>>(x, W1, fxm);
        hipMemsetAsync(fh, 0, (size_t)N_NODES * D * sizeof(float), stream);
        k_scatter<<<(int)(((long long)N_EDGES * D + 255) / 256), 256, 0, stream>>>(src, dst, coef, fxm, fh);
        k_final<<<(N_NODES * D + 255) / 256, 256, 0, stream>>>(fh, fxm, fdis, b1, 1);

        k_gemm32<<<(N_NODES + 7) / 8, 256, 0, stream>>>(fh, W2, fxm);
        hipMemsetAsync(out, 0, (size_t)out_size * sizeof(float), stream);
        k_scatter<<<(int)(((long long)N_EDGES * D + 255) / 256), 256, 0, stream>>>(src, dst, coef, fxm, out);
        k_final<<<(N_NODES * D + 255) / 256, 256, 0, stream>>>(out, fxm, fdis, b2, 0);
    }
}

// Round 4
// 283.510 us; speedup vs baseline: 1.7606x; 1.3908x over previous
//
#include <hip/hip_runtime.h>

#define N_NODES 100000
#define N_EDGES 1600000
#define D 32
#define SCAN_BLK 1024
#define SCAN_NB ((N_NODES + SCAN_BLK - 1) / SCAN_BLK)   // 98
#define FX_SCALE 4294967296.0   // 2^32 fixed-point scale for deg

// ---------------------------------------------------------------- shared bits
// Y[n][j] = sum_k X[n][k] * W[k][j]    (X: [N,32], W: [32,32] row-major)
__global__ void k_gemm32(const float* __restrict__ X, const float* __restrict__ W,
                         float* __restrict__ Y) {
    __shared__ float Ws[D * D];
    __shared__ float Xs[8][D];
    int t = threadIdx.x;  // 256 threads = 8 nodes x 32 features
    for (int i = t; i < D * D; i += 256) Ws[i] = W[i];
    int local = t >> 5, j = t & 31;
    int node = blockIdx.x * 8 + local;
    if (node < N_NODES) Xs[local][j] = X[node * D + j];
    __syncthreads();
    if (node < N_NODES) {
        float acc = 0.f;
#pragma unroll
        for (int k = 0; k < D; ++k) acc = fmaf(Xs[local][k], Ws[k * D + j], acc);
        Y[node * D + j] = acc;
    }
}

// ------------------------------------------------------------- CSR build path
// ONE packed 64-bit atomic per edge: high 16 bits = edge count, low 48 bits =
// weighted degree in 2^-32 fixed point. Returned old value's high bits give
// this edge's position within its dst bucket (replaces a second fill atomic).
__global__ void k_hist2(const int* __restrict__ dst, const float* __restrict__ w,
                        unsigned long long* __restrict__ packed, int* __restrict__ pos) {
    int e = blockIdx.x * blockDim.x + threadIdx.x;
    if (e >= N_EDGES) return;
    int d = dst[e];
    if ((unsigned)d < N_NODES) {
        unsigned long long fx = (unsigned long long)((double)w[e] * FX_SCALE);
        unsigned long long old = atomicAdd(&packed[d], (1ULL << 48) | fx);
        pos[e] = (int)(old >> 48);
    } else {
        pos[e] = 0;
    }
}

// unpack: cnt = high 16 bits; dis = rsqrt(deg + 1)  (+1 = self-loop weight)
__global__ void k_dis2(const unsigned long long* __restrict__ packed,
                       float* __restrict__ dis, int* __restrict__ cnt) {
    int i = blockIdx.x * blockDim.x + threadIdx.x;
    if (i < N_NODES) {
        unsigned long long v = packed[i];
        cnt[i] = (int)(v >> 48);
        float deg = (float)((double)(v & 0xFFFFFFFFFFFFULL) * (1.0 / FX_SCALE));
        dis[i] = rsqrtf(deg + 1.0f);
    }
}

// per-block inclusive scan (Hillis-Steele) + block totals
__global__ void k_scan1(const int* __restrict__ cnt, int* __restrict__ incl,
                        int* __restrict__ bsum) {
    __shared__ int sh[SCAN_BLK];
    int t = threadIdx.x;
    int g = blockIdx.x * SCAN_BLK + t;
    int v = (g < N_NODES) ? cnt[g] : 0;
    sh[t] = v;
    __syncthreads();
    for (int off = 1; off < SCAN_BLK; off <<= 1) {
        int add = (t >= off) ? sh[t - off] : 0;
        __syncthreads();
        sh[t] += add;
        __syncthreads();
    }
    if (g < N_NODES) incl[g] = sh[t];
    if (t == SCAN_BLK - 1) bsum[blockIdx.x] = sh[t];
}

// single-block exclusive scan of the SCAN_NB block totals
__global__ void k_scan2(const int* __restrict__ bsum, int* __restrict__ boffs) {
    __shared__ int sh[256];
    int t = threadIdx.x;
    int v = (t < SCAN_NB) ? bsum[t] : 0;
    sh[t] = v;
    __syncthreads();
    for (int off = 1; off < 256; off <<= 1) {
        int add = (t >= off) ? sh[t - off] : 0;
        __syncthreads();
        sh[t] += add;
        __syncthreads();
    }
    if (t < SCAN_NB) boffs[t] = sh[t] - v;  // exclusive
}

// rowptr (exclusive) = incl - cnt + block offset
__global__ void k_scan3(const int* __restrict__ cnt, const int* __restrict__ incl,
                        const int* __restrict__ boffs, int* __restrict__ rowptr) {
    int g = blockIdx.x * 256 + threadIdx.x;
    if (g < N_NODES) rowptr[g] = incl[g] - cnt[g] + boffs[g / SCAN_BLK];
    if (g == 0) rowptr[N_NODES] = N_EDGES;
}

// place each edge's {coef, src} at rowptr[dst] + pos  — NO atomics
__global__ void k_place(const int* __restrict__ src, const int* __restrict__ dst,
                        const float* __restrict__ w, const int* __restrict__ pos,
                        const float* __restrict__ dis, const int* __restrict__ rowptr,
                        float2* __restrict__ edge2) {
    int e = blockIdx.x * blockDim.x + threadIdx.x;
    if (e >= N_EDGES) return;
    int s = src[e], d = dst[e];
    if ((unsigned)s >= N_NODES || (unsigned)d >= N_NODES) return;
    int slot = rowptr[d] + pos[e];
    float c = dis[s] * w[e] * dis[d];
    edge2[slot] = make_float2(c, __int_as_float(s));
}

// out[n] = [relu]( sum_{e in CSR[n]} coef_e * xm[src_e] + dis[n]^2*xm[n] + b )
// 32 lanes per node (one feature each); 8 nodes per 256-thread block.
__global__ void k_gather(const int* __restrict__ rowptr, const float2* __restrict__ edge2,
                         const float* __restrict__ xm, const float* __restrict__ dis,
                         const float* __restrict__ b, float* __restrict__ out,
                         int do_relu) {
    int t = threadIdx.x;
    int node = blockIdx.x * 8 + (t >> 5);
    int f = t & 31;
    if (node >= N_NODES) return;
    int beg = rowptr[node], end = rowptr[node + 1];
    float acc0 = 0.f, acc1 = 0.f;
    int j = beg;
    for (; j + 1 < end; j += 2) {
        float2 e0 = edge2[j];
        float2 e1 = edge2[j + 1];
        acc0 = fmaf(e0.x, xm[(size_t)__float_as_int(e0.y) * D + f], acc0);
        acc1 = fmaf(e1.x, xm[(size_t)__float_as_int(e1.y) * D + f], acc1);
    }
    if (j < end) {
        float2 e0 = edge2[j];
        acc0 = fmaf(e0.x, xm[(size_t)__float_as_int(e0.y) * D + f], acc0);
    }
    float s = dis[node];
    float v = acc0 + acc1 + s * s * xm[(size_t)node * D + f] + b[f];
    if (do_relu) v = fmaxf(v, 0.f);
    out[(size_t)node * D + f] = v;
}

// ------------------------------------------------- fallback (round-2 atomics)
__global__ void k_hist(const int* __restrict__ dst, const float* __restrict__ w,
                       float* __restrict__ deg) {
    int e = blockIdx.x * blockDim.x + threadIdx.x;
    if (e < N_EDGES) {
        int d = dst[e];
        if ((unsigned)d < N_NODES) atomicAdd(&deg[d], w[e]);
    }
}

__global__ void k_dis(float* __restrict__ deg) {
    int i = blockIdx.x * blockDim.x + threadIdx.x;
    if (i < N_NODES) deg[i] = rsqrtf(deg[i] + 1.0f);
}

__global__ void k_coef(const int* __restrict__ src, const int* __restrict__ dst,
                       const float* __restrict__ w, const float* __restrict__ dis,
                       float* __restrict__ coef) {
    int e = blockIdx.x * blockDim.x + threadIdx.x;
    if (e < N_EDGES) {
        int s = src[e], d = dst[e];
        float c = 0.f;
        if ((unsigned)s < N_NODES && (unsigned)d < N_NODES)
            c = dis[s] * w[e] * dis[d];
        coef[e] = c;
    }
}

__global__ void k_scatter(const int* __restrict__ src, const int* __restrict__ dst,
                          const float* __restrict__ coef, const float* __restrict__ xm,
                          float* __restrict__ out) {
    long long gid = (long long)blockIdx.x * blockDim.x + threadIdx.x;
    if (gid >= (long long)N_EDGES * D) return;
    int e = (int)(gid >> 5);
    int f = (int)(gid & 31);
    int s = src[e], d = dst[e];
    if ((unsigned)s >= N_NODES || (unsigned)d >= N_NODES) return;
    atomicAdd(&out[d * D + f], coef[e] * xm[s * D + f]);
}

__global__ void k_final(float* __restrict__ acc, const float* __restrict__ xm,
                        const float* __restrict__ dis, const float* __restrict__ b,
                        int do_relu) {
    int gid = blockIdx.x * blockDim.x + threadIdx.x;
    if (gid < N_NODES * D) {
        int i = gid >> 5, f = gid & 31;
        float s = dis[i];
        float v = acc[gid] + s * s * xm[gid] + b[f];
        if (do_relu) v = fmaxf(v, 0.f);
        acc[gid] = v;
    }
}

extern "C" void kernel_launch(void* const* d_in, const int* in_sizes, int n_in,
                              void* d_out, int out_size, void* d_ws, size_t ws_size,
                              hipStream_t stream) {
    const float* x  = (const float*)d_in[0];
    const int*   ei = (const int*)d_in[1];   // [2, E] flat: row 0 = src, row 1 = dst
    const float* w  = (const float*)d_in[2];
    const float* W1 = (const float*)d_in[3];
    const float* b1 = (const float*)d_in[4];
    const float* W2 = (const float*)d_in[5];
    const float* b2 = (const float*)d_in[6];
    const int* src = ei;
    const int* dst = ei + N_EDGES;
    float* out = (float*)d_out;

    // ---- CSR-path workspace layout (~40.6 MB; pos aliases xm) ----
    char* p = (char*)d_ws;
    unsigned long long* packed = (unsigned long long*)p;  p += (size_t)N_NODES * 8;
    float2* edge2 = (float2*)p;               p += (size_t)N_EDGES * 8;
    int*   cnt   = (int*)p;                   p += (size_t)N_NODES * 4;
    int*   incl  = (int*)p;                   p += (size_t)N_NODES * 4;
    int*   bsum  = (int*)p;                   p += 256 * 4;
    int*   boffs = (int*)p;                   p += 256 * 4;
    int*   rowptr= (int*)p;                   p += (size_t)(N_NODES + 2) * 4;
    float* dis   = (float*)p;                 p += (size_t)N_NODES * 4;
    float* xm    = (float*)p;                 p += (size_t)N_NODES * D * 4;  // pos aliases this
    float* h     = (float*)p;                 p += (size_t)N_NODES * D * 4;
    int*   pos   = (int*)xm;                  // pos[E] = 6.4 MB <= xm's 12.8 MB
    size_t need = (size_t)(p - (char*)d_ws);

    if (ws_size >= need) {
        // ---- CSR build: exactly ONE atomic per edge ----
        hipMemsetAsync(packed, 0, N_NODES * 8, stream);
        k_hist2<<<(N_EDGES + 255) / 256, 256, 0, stream>>>(dst, w, packed, pos);
        k_dis2<<<(N_NODES + 255) / 256, 256, 0, stream>>>(packed, dis, cnt);
        k_scan1<<<SCAN_NB, SCAN_BLK, 0, stream>>>(cnt, incl, bsum);
        k_scan2<<<1, 256, 0, stream>>>(bsum, boffs);
        k_scan3<<<(N_NODES + 255) / 256, 256, 0, stream>>>(cnt, incl, boffs, rowptr);
        k_place<<<(N_EDGES + 255) / 256, 256, 0, stream>>>(src, dst, w, pos, dis, rowptr, edge2);

        // ---- layer 1: h = relu(A_hat @ (x @ W1) + b1) ----
        k_gemm32<<<(N_NODES + 7) / 8, 256, 0, stream>>>(x, W1, xm);  // overwrites pos (done with it)
        k_gather<<<(N_NODES + 7) / 8, 256, 0, stream>>>(rowptr, edge2, xm, dis, b1, h, 1);

        // ---- layer 2: out = A_hat @ (h @ W2) + b2 ----
        k_gemm32<<<(N_NODES + 7) / 8, 256, 0, stream>>>(h, W2, xm);
        k_gather<<<(N_NODES + 7) / 8, 256, 0, stream>>>(rowptr, edge2, xm, dis, b2, out, 0);
    } else {
        // ---- fallback: round-2 atomic-scatter pipeline (ws >= ~33 MB) ----
        float* fdis  = (float*)d_ws;
        float* coef  = fdis + N_NODES;
        float* fxm   = coef + N_EDGES;
        float* fh    = fxm + (size_t)N_NODES * D;

        hipMemsetAsync(fdis, 0, N_NODES * sizeof(float), stream);
        k_hist<<<(N_EDGES + 255) / 256, 256, 0, stream>>>(dst, w, fdis);
        k_dis<<<(N_NODES + 255) / 256, 256, 0, stream>>>(fdis);
        k_coef<<<(N_EDGES + 255) / 256, 256, 0, stream>>>(src, dst, w, fdis, coef);

        k_gemm32<<<(N_NODES + 7) / 8, 256, 0, stream>>>(x, W1, fxm);
        hipMemsetAsync(fh, 0, (size_t)N_NODES * D * sizeof(float), stream);
        k_scatter<<<(int)(((long long)N_EDGES * D + 255) / 256), 256, 0, stream>>>(src, dst, coef, fxm, fh);
        k_final<<<(N_NODES * D + 255) / 256, 256, 0, stream>>>(fh, fxm, fdis, b1, 1);

        k_gemm32<<<(N_NODES + 7) / 8, 256, 0, stream>>>(fh, W2, fxm);
        hipMemsetAsync(out, 0, (size_t)out_size * sizeof(float), stream);
        k_scatter<<<(int)(((long long)N_EDGES * D + 255) / 256), 256, 0, stream>>>(src, dst, coef, fxm, out);
        k_final<<<(N_NODES * D + 255) / 256, 256, 0, stream>>>(out, fxm, fdis, b2, 0);
    }
}

// Round 5
// 281.931 us; speedup vs baseline: 1.7705x; 1.0056x over previous
//
#include <hip/hip_runtime.h>

#define N_NODES 100000
#define N_EDGES 1600000
#define D 32
#define SCAN_BLK 1024
#define SCAN_NB ((N_NODES + SCAN_BLK - 1) / SCAN_BLK)   // 98
#define FX_SCALE 4294967296.0   // 2^32 fixed-point scale for deg
#define HIST_BLOCKS ((N_EDGES + 255) / 256)             // 6250
#define GEMM_BLOCKS ((N_NODES + 7) / 8)                 // 12500

// ---------------------------------------------------------------------------
// Fused: CSR histogram (one u64 atomic/edge, returns in-bucket rank) + layer-1
// GEMM. Hist blocks first (start atomics ASAP); gemm blocks hide under the
// atomic latency (hist2 alone is 75us at 1% VALUBusy).
__global__ void k_hist_gemm(const int* __restrict__ dst, const float* __restrict__ w,
                            unsigned long long* __restrict__ packed, int* __restrict__ pos,
                            const float* __restrict__ X, const float* __restrict__ W,
                            float* __restrict__ Y) {
    int t = threadIdx.x;
    if (blockIdx.x < HIST_BLOCKS) {
        int e = blockIdx.x * 256 + t;
        if (e >= N_EDGES) return;
        int d = dst[e];
        if ((unsigned)d < N_NODES) {
            unsigned long long fx = (unsigned long long)((double)w[e] * FX_SCALE);
            unsigned long long old = atomicAdd(&packed[d], (1ULL << 48) | fx);
            pos[e] = (int)(old >> 48);
        }
        return;
    }
    // ---- gemm path: Y[n][j] = sum_k X[n][k] * W[k][j] ----
    __shared__ float Ws[D * D];
    __shared__ float Xs[8][D];
    for (int i = t; i < D * D; i += 256) Ws[i] = W[i];
    int local = t >> 5, j = t & 31;
    int node = (blockIdx.x - HIST_BLOCKS) * 8 + local;
    if (node < N_NODES) Xs[local][j] = X[node * D + j];
    __syncthreads();
    if (node < N_NODES) {
        float acc = 0.f;
#pragma unroll
        for (int k = 0; k < D; ++k) acc = fmaf(Xs[local][k], Ws[k * D + j], acc);
        Y[node * D + j] = acc;
    }
}

// plain GEMM for layer 2
__global__ void k_gemm32(const float* __restrict__ X, const float* __restrict__ W,
                         float* __restrict__ Y) {
    __shared__ float Ws[D * D];
    __shared__ float Xs[8][D];
    int t = threadIdx.x;
    for (int i = t; i < D * D; i += 256) Ws[i] = W[i];
    int local = t >> 5, j = t & 31;
    int node = blockIdx.x * 8 + local;
    if (node < N_NODES) Xs[local][j] = X[node * D + j];
    __syncthreads();
    if (node < N_NODES) {
        float acc = 0.f;
#pragma unroll
        for (int k = 0; k < D; ++k) acc = fmaf(Xs[local][k], Ws[k * D + j], acc);
        Y[node * D + j] = acc;
    }
}

// per-block inclusive scan of cnt (unpacked from `packed`) + block totals,
// with dis = rsqrt(deg+1) folded in (replaces the old k_dis2 pass).
__global__ void k_scan1(const unsigned long long* __restrict__ packed,
                        int* __restrict__ incl, int* __restrict__ bsum,
                        float* __restrict__ dis) {
    __shared__ int sh[SCAN_BLK];
    int t = threadIdx.x;
    int g = blockIdx.x * SCAN_BLK + t;
    int v = 0;
    if (g < N_NODES) {
        unsigned long long pk = packed[g];
        v = (int)(pk >> 48);
        float deg = (float)((double)(pk & 0xFFFFFFFFFFFFULL) * (1.0 / FX_SCALE));
        dis[g] = rsqrtf(deg + 1.0f);
    }
    sh[t] = v;
    __syncthreads();
    for (int off = 1; off < SCAN_BLK; off <<= 1) {
        int add = (t >= off) ? sh[t - off] : 0;
        __syncthreads();
        sh[t] += add;
        __syncthreads();
    }
    if (g < N_NODES) incl[g] = sh[t];
    if (t == SCAN_BLK - 1) bsum[blockIdx.x] = sh[t];
}

// single-block exclusive scan of the SCAN_NB block totals
__global__ void k_scan2(const int* __restrict__ bsum, int* __restrict__ boffs) {
    __shared__ int sh[256];
    int t = threadIdx.x;
    int v = (t < SCAN_NB) ? bsum[t] : 0;
    sh[t] = v;
    __syncthreads();
    for (int off = 1; off < 256; off <<= 1) {
        int add = (t >= off) ? sh[t - off] : 0;
        __syncthreads();
        sh[t] += add;
        __syncthreads();
    }
    if (t < SCAN_NB) boffs[t] = sh[t] - v;  // exclusive
}

// rowptr (exclusive) = incl - cnt + block offset
__global__ void k_scan3(const unsigned long long* __restrict__ packed,
                        const int* __restrict__ incl, const int* __restrict__ boffs,
                        int* __restrict__ rowptr) {
    int g = blockIdx.x * 256 + threadIdx.x;
    if (g < N_NODES) {
        int cnt = (int)(packed[g] >> 48);
        rowptr[g] = incl[g] - cnt + boffs[g / SCAN_BLK];
    }
    if (g == 0) rowptr[N_NODES] = N_EDGES;
}

// place each edge's {coef, src} at rowptr[dst] + pos  — NO atomics
__global__ void k_place(const int* __restrict__ src, const int* __restrict__ dst,
                        const float* __restrict__ w, const int* __restrict__ pos,
                        const float* __restrict__ dis, const int* __restrict__ rowptr,
                        float2* __restrict__ edge2) {
    int e = blockIdx.x * blockDim.x + threadIdx.x;
    if (e >= N_EDGES) return;
    int s = src[e], d = dst[e];
    if ((unsigned)s >= N_NODES || (unsigned)d >= N_NODES) return;
    int slot = rowptr[d] + pos[e];
    float c = dis[s] * w[e] * dis[d];
    edge2[slot] = make_float2(c, __int_as_float(s));
}

// out[n] = [relu]( sum_{e in CSR[n]} coef_e * xm[src_e] + dis[n]^2*xm[n] + b )
// ONE node per 64-lane wave: halves split the edge list (stride 2), 2-way
// unrolled per half (4 FMA chains in flight), combined via shfl_xor(32).
__global__ void k_gather(const int* __restrict__ rowptr, const float2* __restrict__ edge2,
                         const float* __restrict__ xm, const float* __restrict__ dis,
                         const float* __restrict__ b, float* __restrict__ out,
                         int do_relu) {
    int t = threadIdx.x;
    int node = blockIdx.x * 4 + (t >> 6);
    int lane = t & 63;
    int f = lane & 31, half = lane >> 5;
    if (node >= N_NODES) return;
    int beg = rowptr[node], end = rowptr[node + 1];
    float a0 = 0.f, a1 = 0.f;
    int j = beg + half;
    for (; j + 2 < end; j += 4) {
        float2 e0 = edge2[j];
        float2 e1 = edge2[j + 2];
        a0 = fmaf(e0.x, xm[(size_t)__float_as_int(e0.y) * D + f], a0);
        a1 = fmaf(e1.x, xm[(size_t)__float_as_int(e1.y) * D + f], a1);
    }
    if (j < end) {
        float2 e0 = edge2[j];
        a0 = fmaf(e0.x, xm[(size_t)__float_as_int(e0.y) * D + f], a0);
    }
    float v = a0 + a1;
    v += __shfl_xor(v, 32, 64);   // combine the two halves
    if (half == 0) {
        float s = dis[node];
        v += s * s * xm[(size_t)node * D + f] + b[f];
        if (do_relu) v = fmaxf(v, 0.f);
        out[(size_t)node * D + f] = v;
    }
}

// ------------------------------------------------- fallback (round-2 atomics)
__global__ void k_hist(const int* __restrict__ dst, const float* __restrict__ w,
                       float* __restrict__ deg) {
    int e = blockIdx.x * blockDim.x + threadIdx.x;
    if (e < N_EDGES) {
        int d = dst[e];
        if ((unsigned)d < N_NODES) atomicAdd(&deg[d], w[e]);
    }
}

__global__ void k_dis(float* __restrict__ deg) {
    int i = blockIdx.x * blockDim.x + threadIdx.x;
    if (i < N_NODES) deg[i] = rsqrtf(deg[i] + 1.0f);
}

__global__ void k_coef(const int* __restrict__ src, const int* __restrict__ dst,
                       const float* __restrict__ w, const float* __restrict__ dis,
                       float* __restrict__ coef) {
    int e = blockIdx.x * blockDim.x + threadIdx.x;
    if (e < N_EDGES) {
        int s = src[e], d = dst[e];
        float c = 0.f;
        if ((unsigned)s < N_NODES && (unsigned)d < N_NODES)
            c = dis[s] * w[e] * dis[d];
        coef[e] = c;
    }
}

__global__ void k_scatter(const int* __restrict__ src, const int* __restrict__ dst,
                          const float* __restrict__ coef, const float* __restrict__ xm,
                          float* __restrict__ out) {
    long long gid = (long long)blockIdx.x * blockDim.x + threadIdx.x;
    if (gid >= (long long)N_EDGES * D) return;
    int e = (int)(gid >> 5);
    int f = (int)(gid & 31);
    int s = src[e], d = dst[e];
    if ((unsigned)s >= N_NODES || (unsigned)d >= N_NODES) return;
    atomicAdd(&out[d * D + f], coef[e] * xm[s * D + f]);
}

__global__ void k_final(float* __restrict__ acc, const float* __restrict__ xm,
                        const float* __restrict__ dis, const float* __restrict__ b,
                        int do_relu) {
    int gid = blockIdx.x * blockDim.x + threadIdx.x;
    if (gid < N_NODES * D) {
        int i = gid >> 5, f = gid & 31;
        float s = dis[i];
        float v = acc[gid] + s * s * xm[gid] + b[f];
        if (do_relu) v = fmaxf(v, 0.f);
        acc[gid] = v;
    }
}

extern "C" void kernel_launch(void* const* d_in, const int* in_sizes, int n_in,
                              void* d_out, int out_size, void* d_ws, size_t ws_size,
                              hipStream_t stream) {
    const float* x  = (const float*)d_in[0];
    const int*   ei = (const int*)d_in[1];   // [2, E] flat: row 0 = src, row 1 = dst
    const float* w  = (const float*)d_in[2];
    const float* W1 = (const float*)d_in[3];
    const float* b1 = (const float*)d_in[4];
    const float* W2 = (const float*)d_in[5];
    const float* b2 = (const float*)d_in[6];
    const int* src = ei;
    const int* dst = ei + N_EDGES;
    float* out = (float*)d_out;

    // ---- workspace layout (~40.2 MB); pos aliases h (NOT xm: gemm1 writes xm
    // concurrently with hist writing pos) ----
    char* p = (char*)d_ws;
    unsigned long long* packed = (unsigned long long*)p;  p += (size_t)N_NODES * 8;
    float2* edge2 = (float2*)p;               p += (size_t)N_EDGES * 8;
    int*   incl  = (int*)p;                   p += (size_t)N_NODES * 4;
    int*   bsum  = (int*)p;                   p += 256 * 4;
    int*   boffs = (int*)p;                   p += 256 * 4;
    int*   rowptr= (int*)p;                   p += (size_t)(N_NODES + 2) * 4;
    float* dis   = (float*)p;                 p += (size_t)N_NODES * 4;
    float* xm    = (float*)p;                 p += (size_t)N_NODES * D * 4;
    float* h     = (float*)p;                 p += (size_t)N_NODES * D * 4;
    int*   pos   = (int*)h;                   // pos[E] = 6.4 MB <= h's 12.8 MB
    size_t need = (size_t)(p - (char*)d_ws);

    if (ws_size >= need) {
        // ---- CSR build + layer-1 GEMM fused under the atomic latency ----
        hipMemsetAsync(packed, 0, N_NODES * 8, stream);
        k_hist_gemm<<<HIST_BLOCKS + GEMM_BLOCKS, 256, 0, stream>>>(
            dst, w, packed, pos, x, W1, xm);
        k_scan1<<<SCAN_NB, SCAN_BLK, 0, stream>>>(packed, incl, bsum, dis);
        k_scan2<<<1, 256, 0, stream>>>(bsum, boffs);
        k_scan3<<<(N_NODES + 255) / 256, 256, 0, stream>>>(packed, incl, boffs, rowptr);
        k_place<<<(N_EDGES + 255) / 256, 256, 0, stream>>>(src, dst, w, pos, dis, rowptr, edge2);

        // ---- layer 1 aggregate: h = relu(A_hat @ xm + b1)  (overwrites pos) ----
        k_gather<<<(N_NODES + 3) / 4, 256, 0, stream>>>(rowptr, edge2, xm, dis, b1, h, 1);

        // ---- layer 2: out = A_hat @ (h @ W2) + b2 ----
        k_gemm32<<<GEMM_BLOCKS, 256, 0, stream>>>(h, W2, xm);
        k_gather<<<(N_NODES + 3) / 4, 256, 0, stream>>>(rowptr, edge2, xm, dis, b2, out, 0);
    } else {
        // ---- fallback: round-2 atomic-scatter pipeline (ws >= ~33 MB) ----
        float* fdis  = (float*)d_ws;
        float* coef  = fdis + N_NODES;
        float* fxm   = coef + N_EDGES;
        float* fh    = fxm + (size_t)N_NODES * D;

        hipMemsetAsync(fdis, 0, N_NODES * sizeof(float), stream);
        k_hist<<<(N_EDGES + 255) / 256, 256, 0, stream>>>(dst, w, fdis);
        k_dis<<<(N_NODES + 255) / 256, 256, 0, stream>>>(fdis);
        k_coef<<<(N_EDGES + 255) / 256, 256, 0, stream>>>(src, dst, w, fdis, coef);

        k_gemm32<<<GEMM_BLOCKS, 256, 0, stream>>>(x, W1, fxm);
        hipMemsetAsync(fh, 0, (size_t)N_NODES * D * sizeof(float), stream);
        k_scatter<<<(int)(((long long)N_EDGES * D + 255) / 256), 256, 0, stream>>>(src, dst, coef, fxm, fh);
        k_final<<<(N_NODES * D + 255) / 256, 256, 0, stream>>>(fh, fxm, fdis, b1, 1);

        k_gemm32<<<GEMM_BLOCKS, 256, 0, stream>>>(fh, W2, fxm);
        hipMemsetAsync(out, 0, (size_t)out_size * sizeof(float), stream);
        k_scatter<<<(int)(((long long)N_EDGES * D + 255) / 256), 256, 0, stream>>>(src, dst, coef, fxm, out);
        k_final<<<(N_NODES * D + 255) / 256, 256, 0, stream>>>(out, fxm, fdis, b2, 0);
    }
}

// Round 6
// 211.039 us; speedup vs baseline: 2.3652x; 1.3359x over previous
//
#include <hip/hip_runtime.h>

#define N_NODES 100000
#define N_EDGES 1600000
#define D 32
#define EPB 4096                                   // edges per level-1 block
#define NBLK ((N_EDGES + EPB - 1) / EPB)           // 391 level-1 blocks
#define NBC ((N_NODES + 255) / 256)                // 391 coarse buckets (256 nodes each)
#define NBB (NBC * NBLK)                           // 152881 scan entries
#define SCAN_BLK 1024
#define SNB1 ((NBB + SCAN_BLK - 1) / SCAN_BLK)     // 150
#define WFX_SCALE 67108864.0f                      // 2^26 fixed point for deg

// --------------------------------------------------------------- level-1 count
// Per-block LDS histogram over 391 coarse buckets; plain global stores.
__global__ void k_bcount(const int* __restrict__ dst, int* __restrict__ bhist) {
    __shared__ int hist[NBC];
    int t = threadIdx.x;
    for (int i = t; i < NBC; i += 1024) hist[i] = 0;
    __syncthreads();
    int base = blockIdx.x * EPB;
#pragma unroll
    for (int i = 0; i < 4; ++i) {
        int e = base + i * 1024 + t;
        if (e < N_EDGES) {
            int d = dst[e];
            if ((unsigned)d < N_NODES) atomicAdd(&hist[d >> 8], 1);
        }
    }
    __syncthreads();
    for (int c = t; c < NBC; c += 1024) bhist[c * NBLK + blockIdx.x] = hist[c];
}

// ----------------------------------------------------------------- scans (n)
__global__ void k_scan1(const int* __restrict__ in, int* __restrict__ incl,
                        int* __restrict__ bsum, int n) {
    __shared__ int sh[SCAN_BLK];
    int t = threadIdx.x;
    int g = blockIdx.x * SCAN_BLK + t;
    int v = (g < n) ? in[g] : 0;
    sh[t] = v;
    __syncthreads();
    for (int off = 1; off < SCAN_BLK; off <<= 1) {
        int add = (t >= off) ? sh[t - off] : 0;
        __syncthreads();
        sh[t] += add;
        __syncthreads();
    }
    if (g < n) incl[g] = sh[t];
    if (t == SCAN_BLK - 1) bsum[blockIdx.x] = sh[t];
}

__global__ void k_scan2(const int* __restrict__ bsum, int* __restrict__ boffs, int nb) {
    __shared__ int sh[256];
    int t = threadIdx.x;
    int v = (t < nb) ? bsum[t] : 0;
    sh[t] = v;
    __syncthreads();
    for (int off = 1; off < 256; off <<= 1) {
        int add = (t >= off) ? sh[t - off] : 0;
        __syncthreads();
        sh[t] += add;
        __syncthreads();
    }
    if (t < nb) boffs[t] = sh[t] - v;  // exclusive
}

__global__ void k_scan3(const int* __restrict__ in, const int* __restrict__ incl,
                        const int* __restrict__ boffs, int* __restrict__ outp, int n) {
    int g = blockIdx.x * 256 + threadIdx.x;
    if (g < n) outp[g] = incl[g] - in[g] + boffs[g / SCAN_BLK];
}

// -------------------------------------------------------------- level-1 scatter
// Re-rank via LDS atomics (unique within (block,bucket); order irrelevant) and
// write {src | dlow<<20, w_bits} to bucket-contiguous storage. No global atomics.
__global__ void k_bscatter(const int* __restrict__ src, const int* __restrict__ dst,
                           const float* __restrict__ w, const int* __restrict__ sbase,
                           uint2* __restrict__ bucketed) {
    __shared__ int hist[NBC];
    __shared__ int lsb[NBC];
    int t = threadIdx.x;
    for (int i = t; i < NBC; i += 1024) {
        hist[i] = 0;
        lsb[i] = sbase[i * NBLK + blockIdx.x];
    }
    __syncthreads();
    int base = blockIdx.x * EPB;
#pragma unroll
    for (int i = 0; i < 4; ++i) {
        int e = base + i * 1024 + t;
        if (e < N_EDGES) {
            int d = dst[e];
            if ((unsigned)d < N_NODES) {
                int c = d >> 8;
                int r = atomicAdd(&hist[c], 1);
                uint2 rec;
                rec.x = ((unsigned)src[e] & 0xFFFFFu) | ((unsigned)(d & 255) << 20);
                rec.y = __float_as_uint(w[e]);
                bucketed[lsb[c] + r] = rec;
            }
        }
    }
}

// ----------------------------------------------------- level-2 CSR finalization
// One block per coarse bucket: LDS count + fixed-point w-sum per node (deg),
// LDS scan -> rowptr, LDS-rank placement -> final CSR edge2 = {w, src}.
__global__ void k_build(const int* __restrict__ sbase, const uint2* __restrict__ bucketed,
                        int* __restrict__ rowptr, float* __restrict__ deg,
                        float2* __restrict__ edge2) {
    __shared__ int cnt[256], lb[256], fill[256], sh[256];
    __shared__ unsigned wfx[256];
    int t = threadIdx.x, c = blockIdx.x;
    cnt[t] = 0; fill[t] = 0; wfx[t] = 0;
    __syncthreads();
    int beg = sbase[c * NBLK];
    int end = (c == NBC - 1) ? N_EDGES : sbase[(c + 1) * NBLK];
    for (int i = beg + t; i < end; i += 256) {
        uint2 rec = bucketed[i];
        int dlow = rec.x >> 20;
        atomicAdd(&cnt[dlow], 1);
        atomicAdd(&wfx[dlow], (unsigned)(__uint_as_float(rec.y) * WFX_SCALE));
    }
    __syncthreads();
    int v = cnt[t];
    sh[t] = v;
    __syncthreads();
    for (int off = 1; off < 256; off <<= 1) {
        int add = (t >= off) ? sh[t - off] : 0;
        __syncthreads();
        sh[t] += add;
        __syncthreads();
    }
    int ex = sh[t] - v;
    lb[t] = ex;
    int node = c * 256 + t;
    if (node < N_NODES) {
        rowptr[node] = beg + ex;
        deg[node] = (float)wfx[t] * (1.0f / WFX_SCALE);
    }
    __syncthreads();
    for (int i = beg + t; i < end; i += 256) {
        uint2 rec = bucketed[i];
        int dlow = rec.x >> 20;
        int r = atomicAdd(&fill[dlow], 1);
        float2 e2;
        e2.x = __uint_as_float(rec.y);                       // w
        e2.y = __int_as_float((int)(rec.x & 0xFFFFFu));      // src
        edge2[beg + lb[dlow] + r] = e2;
    }
}

// deg -> dis = rsqrt(deg + 1) in place; also closes rowptr
__global__ void k_dis(float* __restrict__ dis, int* __restrict__ rowptr) {
    int i = blockIdx.x * blockDim.x + threadIdx.x;
    if (i < N_NODES) dis[i] = rsqrtf(dis[i] + 1.0f);
    if (i == 0) rowptr[N_NODES] = N_EDGES;
}

// ------------------------------------------------------------------------ GEMM
__global__ void k_gemm32(const float* __restrict__ X, const float* __restrict__ W,
                         float* __restrict__ Y) {
    __shared__ float Ws[D * D];
    __shared__ float Xs[8][D];
    int t = threadIdx.x;
    for (int i = t; i < D * D; i += 256) Ws[i] = W[i];
    int local = t >> 5, j = t & 31;
    int node = blockIdx.x * 8 + local;
    if (node < N_NODES) Xs[local][j] = X[node * D + j];
    __syncthreads();
    if (node < N_NODES) {
        float acc = 0.f;
#pragma unroll
        for (int k = 0; k < D; ++k) acc = fmaf(Xs[local][k], Ws[k * D + j], acc);
        Y[node * D + j] = acc;
    }
}

// ---------------------------------------------------------------------- gather
// out[n] = [relu]( dis[n]*( sum_e dis[src]*w*xm[src] + dis[n]*xm[n] ) + b )
// One node per 64-lane wave; halves split the edge list, 2-way unrolled.
__global__ void k_gather(const int* __restrict__ rowptr, const float2* __restrict__ edge2,
                         const float* __restrict__ xm, const float* __restrict__ dis,
                         const float* __restrict__ b, float* __restrict__ out,
                         int do_relu) {
    int t = threadIdx.x;
    int node = blockIdx.x * 4 + (t >> 6);
    int lane = t & 63;
    int f = lane & 31, half = lane >> 5;
    if (node >= N_NODES) return;
    int beg = rowptr[node], end = rowptr[node + 1];
    float a0 = 0.f, a1 = 0.f;
    int j = beg + half;
    for (; j + 2 < end; j += 4) {
        float2 e0 = edge2[j];
        float2 e1 = edge2[j + 2];
        int s0 = __float_as_int(e0.y), s1 = __float_as_int(e1.y);
        a0 = fmaf(dis[s0] * e0.x, xm[(size_t)s0 * D + f], a0);
        a1 = fmaf(dis[s1] * e1.x, xm[(size_t)s1 * D + f], a1);
    }
    if (j < end) {
        float2 e0 = edge2[j];
        int s0 = __float_as_int(e0.y);
        a0 = fmaf(dis[s0] * e0.x, xm[(size_t)s0 * D + f], a0);
    }
    float vsum = a0 + a1;
    vsum += __shfl_xor(vsum, 32, 64);   // combine the two halves
    if (half == 0) {
        float s = dis[node];
        float vout = s * (vsum + s * xm[(size_t)node * D + f]) + b[f];
        if (do_relu) vout = fmaxf(vout, 0.f);
        out[(size_t)node * D + f] = vout;
    }
}

// ------------------------------------------------- fallback (atomic pipeline)
__global__ void k_hist(const int* __restrict__ dst, const float* __restrict__ w,
                       float* __restrict__ deg) {
    int e = blockIdx.x * blockDim.x + threadIdx.x;
    if (e < N_EDGES) {
        int d = dst[e];
        if ((unsigned)d < N_NODES) atomicAdd(&deg[d], w[e]);
    }
}

__global__ void k_coef(const int* __restrict__ src, const int* __restrict__ dst,
                       const float* __restrict__ w, const float* __restrict__ dis,
                       float* __restrict__ coef) {
    int e = blockIdx.x * blockDim.x + threadIdx.x;
    if (e < N_EDGES) {
        int s = src[e], d = dst[e];
        float c = 0.f;
        if ((unsigned)s < N_NODES && (unsigned)d < N_NODES)
            c = dis[s] * w[e] * dis[d];
        coef[e] = c;
    }
}

__global__ void k_scatter(const int* __restrict__ src, const int* __restrict__ dst,
                          const float* __restrict__ coef, const float* __restrict__ xm,
                          float* __restrict__ out) {
    long long gid = (long long)blockIdx.x * blockDim.x + threadIdx.x;
    if (gid >= (long long)N_EDGES * D) return;
    int e = (int)(gid >> 5);
    int f = (int)(gid & 31);
    int s = src[e], d = dst[e];
    if ((unsigned)s >= N_NODES || (unsigned)d >= N_NODES) return;
    atomicAdd(&out[d * D + f], coef[e] * xm[s * D + f]);
}

__global__ void k_final(float* __restrict__ acc, const float* __restrict__ xm,
                        const float* __restrict__ dis, const float* __restrict__ b,
                        int do_relu) {
    int gid = blockIdx.x * blockDim.x + threadIdx.x;
    if (gid < N_NODES * D) {
        int i = gid >> 5, f = gid & 31;
        float s = dis[i];
        float v = acc[gid] + s * s * xm[gid] + b[f];
        if (do_relu) v = fmaxf(v, 0.f);
        acc[gid] = v;
    }
}

extern "C" void kernel_launch(void* const* d_in, const int* in_sizes, int n_in,
                              void* d_out, int out_size, void* d_ws, size_t ws_size,
                              hipStream_t stream) {
    const float* x  = (const float*)d_in[0];
    const int*   ei = (const int*)d_in[1];   // [2, E] flat: row 0 = src, row 1 = dst
    const float* w  = (const float*)d_in[2];
    const float* W1 = (const float*)d_in[3];
    const float* b1 = (const float*)d_in[4];
    const float* W2 = (const float*)d_in[5];
    const float* b2 = (const float*)d_in[6];
    const int* src = ei;
    const int* dst = ei + N_EDGES;
    float* out = (float*)d_out;

    // ---- workspace layout (~40.24 MB, all 8B-aligned chunks) ----
    // bucketed[E] (uint2, later aliased by xm) | edge2[E] (float2) | h[N*D] |
    // bhist[NBB] (later aliased by dis) | incl[NBB] (later aliased by rowptr) |
    // sbase[NBB] | bsum | boffs
    char* p = (char*)d_ws;
    uint2*  bucketed = (uint2*)p;   p += (size_t)N_EDGES * 8;
    float2* edge2    = (float2*)p;  p += (size_t)N_EDGES * 8;
    float*  h        = (float*)p;   p += (size_t)N_NODES * D * 4;
    int*    bhist    = (int*)p;     p += (size_t)NBB * 4 + 4;
    int*    incl     = (int*)p;     p += (size_t)NBB * 4 + 4;
    int*    sbase    = (int*)p;     p += (size_t)NBB * 4 + 4;
    int*    bsum     = (int*)p;     p += 1024;
    int*    boffs    = (int*)p;     p += 1024;
    size_t need = (size_t)(p - (char*)d_ws);

    float* xm     = (float*)bucketed;  // live after k_build is done with bucketed
    int*   rowptr = incl;              // live after k_scan3 is done with incl
    float* dis    = (float*)bhist;     // live after k_scan3 is done with bhist

    if (ws_size >= need) {
        // ---- CSR build: zero global atomics ----
        k_bcount<<<NBLK, 1024, 0, stream>>>(dst, bhist);
        k_scan1<<<SNB1, SCAN_BLK, 0, stream>>>(bhist, incl, bsum, NBB);
        k_scan2<<<1, 256, 0, stream>>>(bsum, boffs, SNB1);
        k_scan3<<<(NBB + 255) / 256, 256, 0, stream>>>(bhist, incl, boffs, sbase, NBB);
        k_bscatter<<<NBLK, 1024, 0, stream>>>(src, dst, w, sbase, bucketed);
        k_build<<<NBC, 256, 0, stream>>>(sbase, bucketed, rowptr, dis, edge2);
        k_dis<<<(N_NODES + 255) / 256, 256, 0, stream>>>(dis, rowptr);

        // ---- layer 1: h = relu(A_hat @ (x @ W1) + b1) ----
        k_gemm32<<<(N_NODES + 7) / 8, 256, 0, stream>>>(x, W1, xm);
        k_gather<<<(N_NODES + 3) / 4, 256, 0, stream>>>(rowptr, edge2, xm, dis, b1, h, 1);

        // ---- layer 2: out = A_hat @ (h @ W2) + b2 ----
        k_gemm32<<<(N_NODES + 7) / 8, 256, 0, stream>>>(h, W2, xm);
        k_gather<<<(N_NODES + 3) / 4, 256, 0, stream>>>(rowptr, edge2, xm, dis, b2, out, 0);
    } else {
        // ---- fallback: atomic-scatter pipeline (ws >= ~33 MB) ----
        float* fdis  = (float*)d_ws;
        float* coef  = fdis + N_NODES;
        float* fxm   = coef + N_EDGES;
        float* fh    = fxm + (size_t)N_NODES * D;

        hipMemsetAsync(fdis, 0, N_NODES * sizeof(float), stream);
        k_hist<<<(N_EDGES + 255) / 256, 256, 0, stream>>>(dst, w, fdis);
        k_dis<<<(N_NODES + 255) / 256, 256, 0, stream>>>(fdis, (int*)coef);  // rowptr write lands in scratch
        k_coef<<<(N_EDGES + 255) / 256, 256, 0, stream>>>(src, dst, w, fdis, coef);

        k_gemm32<<<(N_NODES + 7) / 8, 256, 0, stream>>>(x, W1, fxm);
        hipMemsetAsync(fh, 0, (size_t)N_NODES * D * sizeof(float), stream);
        k_scatter<<<(int)(((long long)N_EDGES * D + 255) / 256), 256, 0, stream>>>(src, dst, coef, fxm, fh);
        k_final<<<(N_NODES * D + 255) / 256, 256, 0, stream>>>(fh, fxm, fdis, b1, 1);

        k_gemm32<<<(N_NODES + 7) / 8, 256, 0, stream>>>(fh, W2, fxm);
        hipMemsetAsync(out, 0, (size_t)out_size * sizeof(float), stream);
        k_scatter<<<(int)(((long long)N_EDGES * D + 255) / 256), 256, 0, stream>>>(src, dst, coef, fxm, out);
        k_final<<<(N_NODES * D + 255) / 256, 256, 0, stream>>>(out, fxm, fdis, b2, 0);
    }
}

// Round 7
// 189.157 us; speedup vs baseline: 2.6388x; 1.1157x over previous
//
#include <hip/hip_runtime.h>
#include <hip/hip_fp16.h>

#define N_NODES 100000
#define N_EDGES 1600000
#define D 32
#define EPB 4096                                   // edges per level-1 block
#define NBLK ((N_EDGES + EPB - 1) / EPB)           // 391 level-1 blocks
#define NBC ((N_NODES + 255) / 256)                // 391 coarse buckets (256 nodes each)
#define NBB (NBC * NBLK)                           // 152881 scan entries
#define SCAN_BLK 1024
#define SNB1 ((NBB + SCAN_BLK - 1) / SCAN_BLK)     // 150
#define WFX_SCALE 67108864.0f                      // 2^26 fixed point for deg

// --------------------------------------------------------------- level-1 count
__global__ void k_bcount(const int* __restrict__ dst, int* __restrict__ bhist) {
    __shared__ int hist[NBC];
    int t = threadIdx.x;
    for (int i = t; i < NBC; i += 1024) hist[i] = 0;
    __syncthreads();
    int base = blockIdx.x * EPB;
#pragma unroll
    for (int i = 0; i < 4; ++i) {
        int e = base + i * 1024 + t;
        if (e < N_EDGES) {
            int d = dst[e];
            if ((unsigned)d < N_NODES) atomicAdd(&hist[d >> 8], 1);
        }
    }
    __syncthreads();
    for (int c = t; c < NBC; c += 1024) bhist[c * NBLK + blockIdx.x] = hist[c];
}

// ----------------------------------------------------------------- scans (n)
__global__ void k_scan1(const int* __restrict__ in, int* __restrict__ incl,
                        int* __restrict__ bsum, int n) {
    __shared__ int sh[SCAN_BLK];
    int t = threadIdx.x;
    int g = blockIdx.x * SCAN_BLK + t;
    int v = (g < n) ? in[g] : 0;
    sh[t] = v;
    __syncthreads();
    for (int off = 1; off < SCAN_BLK; off <<= 1) {
        int add = (t >= off) ? sh[t - off] : 0;
        __syncthreads();
        sh[t] += add;
        __syncthreads();
    }
    if (g < n) incl[g] = sh[t];
    if (t == SCAN_BLK - 1) bsum[blockIdx.x] = sh[t];
}

__global__ void k_scan2(const int* __restrict__ bsum, int* __restrict__ boffs, int nb) {
    __shared__ int sh[256];
    int t = threadIdx.x;
    int v = (t < nb) ? bsum[t] : 0;
    sh[t] = v;
    __syncthreads();
    for (int off = 1; off < 256; off <<= 1) {
        int add = (t >= off) ? sh[t - off] : 0;
        __syncthreads();
        sh[t] += add;
        __syncthreads();
    }
    if (t < nb) boffs[t] = sh[t] - v;  // exclusive
}

__global__ void k_scan3(const int* __restrict__ in, const int* __restrict__ incl,
                        const int* __restrict__ boffs, int* __restrict__ outp, int n) {
    int g = blockIdx.x * 256 + threadIdx.x;
    if (g < n) outp[g] = incl[g] - in[g] + boffs[g / SCAN_BLK];
}

// -------------------------------------------------------------- level-1 scatter
__global__ void k_bscatter(const int* __restrict__ src, const int* __restrict__ dst,
                           const float* __restrict__ w, const int* __restrict__ sbase,
                           uint2* __restrict__ bucketed) {
    __shared__ int hist[NBC];
    __shared__ int lsb[NBC];
    int t = threadIdx.x;
    for (int i = t; i < NBC; i += 1024) {
        hist[i] = 0;
        lsb[i] = sbase[i * NBLK + blockIdx.x];
    }
    __syncthreads();
    int base = blockIdx.x * EPB;
#pragma unroll
    for (int i = 0; i < 4; ++i) {
        int e = base + i * 1024 + t;
        if (e < N_EDGES) {
            int d = dst[e];
            if ((unsigned)d < N_NODES) {
                int c = d >> 8;
                int r = atomicAdd(&hist[c], 1);
                uint2 rec;
                rec.x = ((unsigned)src[e] & 0xFFFFFu) | ((unsigned)(d & 255) << 20);
                rec.y = __float_as_uint(w[e]);
                bucketed[lsb[c] + r] = rec;
            }
        }
    }
}

// ----------------------------------------------------- level-2 CSR finalization
// One block per coarse bucket: LDS count + fixed-point w-sum (deterministic deg),
// LDS scan -> rowptr, LDS-rank placement -> edge2 = {w, src}. dis written direct.
__global__ void k_build(const int* __restrict__ sbase, const uint2* __restrict__ bucketed,
                        int* __restrict__ rowptr, float* __restrict__ dis,
                        float2* __restrict__ edge2) {
    __shared__ int cnt[256], lb[256], fill[256], sh[256];
    __shared__ unsigned wfx[256];
    int t = threadIdx.x, c = blockIdx.x;
    cnt[t] = 0; fill[t] = 0; wfx[t] = 0;
    __syncthreads();
    int beg = sbase[c * NBLK];
    int end = (c == NBC - 1) ? N_EDGES : sbase[(c + 1) * NBLK];
    for (int i = beg + t; i < end; i += 256) {
        uint2 rec = bucketed[i];
        int dlow = rec.x >> 20;
        atomicAdd(&cnt[dlow], 1);
        atomicAdd(&wfx[dlow], (unsigned)(__uint_as_float(rec.y) * WFX_SCALE));
    }
    __syncthreads();
    int v = cnt[t];
    sh[t] = v;
    __syncthreads();
    for (int off = 1; off < 256; off <<= 1) {
        int add = (t >= off) ? sh[t - off] : 0;
        __syncthreads();
        sh[t] += add;
        __syncthreads();
    }
    int ex = sh[t] - v;
    lb[t] = ex;
    int node = c * 256 + t;
    if (node < N_NODES) {
        rowptr[node] = beg + ex;
        float deg = (float)wfx[t] * (1.0f / WFX_SCALE);
        dis[node] = rsqrtf(deg + 1.0f);
    }
    if (c == 0 && t == 0) rowptr[N_NODES] = N_EDGES;
    __syncthreads();
    for (int i = beg + t; i < end; i += 256) {
        uint2 rec = bucketed[i];
        int dlow = rec.x >> 20;
        int r = atomicAdd(&fill[dlow], 1);
        float2 e2;
        e2.x = __uint_as_float(rec.y);                       // w
        e2.y = __int_as_float((int)(rec.x & 0xFFFFFu));      // src
        edge2[beg + lb[dlow] + r] = e2;
    }
}

// ---------------------------------------------------------------- GEMM (fp16 out)
// Y[n][j] = dis[n] * sum_k X[n][k] * W[k][j], stored half (dis pre-folded)
__global__ void k_gemm32h(const float* __restrict__ X, const float* __restrict__ W,
                          const float* __restrict__ dis, __half* __restrict__ Y) {
    __shared__ float Ws[D * D];
    __shared__ float Xs[8][D];
    int t = threadIdx.x;
    for (int i = t; i < D * D; i += 256) Ws[i] = W[i];
    int local = t >> 5, j = t & 31;
    int node = blockIdx.x * 8 + local;
    if (node < N_NODES) Xs[local][j] = X[node * D + j];
    __syncthreads();
    if (node < N_NODES) {
        float acc = 0.f;
#pragma unroll
        for (int k = 0; k < D; ++k) acc = fmaf(Xs[local][k], Ws[k * D + j], acc);
        Y[(size_t)node * D + j] = __float2half(acc * dis[node]);
    }
}

// ------------------------------------------------------------- gather + fused W2
// h[n][f] = relu( dis[n]*( sum_e w_e*xms[src_e][f] + xms[n][f] ) + b1[f] )
// y[n][j] = dis[n] * sum_f h[n][f]*W2[f][j]   (stored half; dis pre-folded)
// One node per 64-lane wave; halves interleave the edge list, 4-way unrolled.
__global__ void k_gather_mid(const int* __restrict__ rowptr, const float2* __restrict__ edge2,
                             const __half* __restrict__ xm, const float* __restrict__ dis,
                             const float* __restrict__ b, const float* __restrict__ W2,
                             __half* __restrict__ y) {
    __shared__ float W2s[D * D];
    int t = threadIdx.x;
    for (int i = t; i < D * D; i += 256) W2s[i] = W2[i];
    __syncthreads();
    int node = blockIdx.x * 4 + (t >> 6);
    if (node >= N_NODES) return;
    int lane = t & 63;
    int f = lane & 31, half = lane >> 5;
    int beg = rowptr[node], end = rowptr[node + 1];
    float a0 = 0.f, a1 = 0.f, a2 = 0.f, a3 = 0.f;
    int j = beg + half;
    for (; j + 6 < end; j += 8) {
        float2 e0 = edge2[j],     e1 = edge2[j + 2];
        float2 e2 = edge2[j + 4], e3 = edge2[j + 6];
        a0 = fmaf(e0.x, __half2float(xm[(size_t)__float_as_int(e0.y) * D + f]), a0);
        a1 = fmaf(e1.x, __half2float(xm[(size_t)__float_as_int(e1.y) * D + f]), a1);
        a2 = fmaf(e2.x, __half2float(xm[(size_t)__float_as_int(e2.y) * D + f]), a2);
        a3 = fmaf(e3.x, __half2float(xm[(size_t)__float_as_int(e3.y) * D + f]), a3);
    }
    for (; j < end; j += 2) {
        float2 e0 = edge2[j];
        a0 = fmaf(e0.x, __half2float(xm[(size_t)__float_as_int(e0.y) * D + f]), a0);
    }
    float v = (a0 + a1) + (a2 + a3);
    v += __shfl_xor(v, 32, 64);               // both halves now hold full edge sum
    float s = dis[node];
    float hval = s * (v + __half2float(xm[(size_t)node * D + f])) + b[f];
    hval = fmaxf(hval, 0.f);
    // fused h @ W2: lane f holds h[f]; halves split the k-sum, combine, store.
    float acc = 0.f;
#pragma unroll
    for (int k = 0; k < 16; ++k) {
        int ff = k + half * 16;
        float hf = __shfl(hval, ff, 64);
        acc = fmaf(hf, W2s[ff * D + f], acc);
    }
    acc += __shfl_xor(acc, 32, 64);
    if (half == 0) y[(size_t)node * D + f] = __float2half(s * acc);
}

// ------------------------------------------------------------------ final gather
// out[n][f] = dis[n]*( sum_e w_e*xms[src_e][f] + xms[n][f] ) + b2[f]
__global__ void k_gather_out(const int* __restrict__ rowptr, const float2* __restrict__ edge2,
                             const __half* __restrict__ xm, const float* __restrict__ dis,
                             const float* __restrict__ b, float* __restrict__ out) {
    int t = threadIdx.x;
    int node = blockIdx.x * 4 + (t >> 6);
    if (node >= N_NODES) return;
    int lane = t & 63;
    int f = lane & 31, half = lane >> 5;
    int beg = rowptr[node], end = rowptr[node + 1];
    float a0 = 0.f, a1 = 0.f, a2 = 0.f, a3 = 0.f;
    int j = beg + half;
    for (; j + 6 < end; j += 8) {
        float2 e0 = edge2[j],     e1 = edge2[j + 2];
        float2 e2 = edge2[j + 4], e3 = edge2[j + 6];
        a0 = fmaf(e0.x, __half2float(xm[(size_t)__float_as_int(e0.y) * D + f]), a0);
        a1 = fmaf(e1.x, __half2float(xm[(size_t)__float_as_int(e1.y) * D + f]), a1);
        a2 = fmaf(e2.x, __half2float(xm[(size_t)__float_as_int(e2.y) * D + f]), a2);
        a3 = fmaf(e3.x, __half2float(xm[(size_t)__float_as_int(e3.y) * D + f]), a3);
    }
    for (; j < end; j += 2) {
        float2 e0 = edge2[j];
        a0 = fmaf(e0.x, __half2float(xm[(size_t)__float_as_int(e0.y) * D + f]), a0);
    }
    float v = (a0 + a1) + (a2 + a3);
    v += __shfl_xor(v, 32, 64);
    if (half == 0) {
        float s = dis[node];
        out[(size_t)node * D + f] = s * (v + __half2float(xm[(size_t)node * D + f])) + b[f];
    }
}

// ------------------------------------------------- fallback (atomic pipeline)
__global__ void k_hist(const int* __restrict__ dst, const float* __restrict__ w,
                       float* __restrict__ deg) {
    int e = blockIdx.x * blockDim.x + threadIdx.x;
    if (e < N_EDGES) {
        int d = dst[e];
        if ((unsigned)d < N_NODES) atomicAdd(&deg[d], w[e]);
    }
}

__global__ void k_disf(float* __restrict__ deg) {
    int i = blockIdx.x * blockDim.x + threadIdx.x;
    if (i < N_NODES) deg[i] = rsqrtf(deg[i] + 1.0f);
}

__global__ void k_coef(const int* __restrict__ src, const int* __restrict__ dst,
                       const float* __restrict__ w, const float* __restrict__ dis,
                       float* __restrict__ coef) {
    int e = blockIdx.x * blockDim.x + threadIdx.x;
    if (e < N_EDGES) {
        int s = src[e], d = dst[e];
        float c = 0.f;
        if ((unsigned)s < N_NODES && (unsigned)d < N_NODES)
            c = dis[s] * w[e] * dis[d];
        coef[e] = c;
    }
}

__global__ void k_gemm32f(const float* __restrict__ X, const float* __restrict__ W,
                          float* __restrict__ Y) {
    __shared__ float Ws[D * D];
    __shared__ float Xs[8][D];
    int t = threadIdx.x;
    for (int i = t; i < D * D; i += 256) Ws[i] = W[i];
    int local = t >> 5, j = t & 31;
    int node = blockIdx.x * 8 + local;
    if (node < N_NODES) Xs[local][j] = X[node * D + j];
    __syncthreads();
    if (node < N_NODES) {
        float acc = 0.f;
#pragma unroll
        for (int k = 0; k < D; ++k) acc = fmaf(Xs[local][k], Ws[k * D + j], acc);
        Y[node * D + j] = acc;
    }
}

__global__ void k_scatter(const int* __restrict__ src, const int* __restrict__ dst,
                          const float* __restrict__ coef, const float* __restrict__ xm,
                          float* __restrict__ out) {
    long long gid = (long long)blockIdx.x * blockDim.x + threadIdx.x;
    if (gid >= (long long)N_EDGES * D) return;
    int e = (int)(gid >> 5);
    int f = (int)(gid & 31);
    int s = src[e], d = dst[e];
    if ((unsigned)s >= N_NODES || (unsigned)d >= N_NODES) return;
    atomicAdd(&out[d * D + f], coef[e] * xm[s * D + f]);
}

__global__ void k_final(float* __restrict__ acc, const float* __restrict__ xm,
                        const float* __restrict__ dis, const float* __restrict__ b,
                        int do_relu) {
    int gid = blockIdx.x * blockDim.x + threadIdx.x;
    if (gid < N_NODES * D) {
        int i = gid >> 5, f = gid & 31;
        float s = dis[i];
        float v = acc[gid] + s * s * xm[gid] + b[f];
        if (do_relu) v = fmaxf(v, 0.f);
        acc[gid] = v;
    }
}

extern "C" void kernel_launch(void* const* d_in, const int* in_sizes, int n_in,
                              void* d_out, int out_size, void* d_ws, size_t ws_size,
                              hipStream_t stream) {
    const float* x  = (const float*)d_in[0];
    const int*   ei = (const int*)d_in[1];   // [2, E] flat: row 0 = src, row 1 = dst
    const float* w  = (const float*)d_in[2];
    const float* W1 = (const float*)d_in[3];
    const float* b1 = (const float*)d_in[4];
    const float* W2 = (const float*)d_in[5];
    const float* b2 = (const float*)d_in[6];
    const int* src = ei;
    const int* dst = ei + N_EDGES;
    float* out = (float*)d_out;

    // ---- workspace layout (~27.5 MB) ----
    // bucketed[E] uint2 (after k_build: xm1s half at lo 6.4MB, xm2s half at hi 6.4MB)
    // edge2[E] float2 | bhist[NBB]->dis | incl[NBB]->rowptr | sbase[NBB] | bsum | boffs
    char* p = (char*)d_ws;
    uint2*  bucketed = (uint2*)p;   p += (size_t)N_EDGES * 8;
    float2* edge2    = (float2*)p;  p += (size_t)N_EDGES * 8;
    int*    bhist    = (int*)p;     p += (size_t)NBB * 4 + 4;
    int*    incl     = (int*)p;     p += (size_t)NBB * 4 + 4;
    int*    sbase    = (int*)p;     p += (size_t)NBB * 4 + 4;
    int*    bsum     = (int*)p;     p += 1024;
    int*    boffs    = (int*)p;     p += 1024;
    size_t need = (size_t)(p - (char*)d_ws);

    __half* xm1s  = (__half*)bucketed;                          // 6.4 MB
    __half* xm2s  = (__half*)bucketed + (size_t)N_NODES * D;    // next 6.4 MB
    int*    rowptr = incl;             // live after k_scan3 consumed incl
    float*  dis    = (float*)bhist;    // live after k_scan3 consumed bhist

    if (ws_size >= need) {
        // ---- CSR build: zero global atomics; dis folded into k_build ----
        k_bcount<<<NBLK, 1024, 0, stream>>>(dst, bhist);
        k_scan1<<<SNB1, SCAN_BLK, 0, stream>>>(bhist, incl, bsum, NBB);
        k_scan2<<<1, 256, 0, stream>>>(bsum, boffs, SNB1);
        k_scan3<<<(NBB + 255) / 256, 256, 0, stream>>>(bhist, incl, boffs, sbase, NBB);
        k_bscatter<<<NBLK, 1024, 0, stream>>>(src, dst, w, sbase, bucketed);
        k_build<<<NBC, 256, 0, stream>>>(sbase, bucketed, rowptr, dis, edge2);

        // ---- layer 1 GEMM: xm1s = dis * (x @ W1), fp16 (overwrites bucketed lo) ----
        k_gemm32h<<<(N_NODES + 7) / 8, 256, 0, stream>>>(x, W1, dis, xm1s);
        // ---- gather1 + bias/relu + fused @W2 + dis-scale -> xm2s fp16 ----
        k_gather_mid<<<(N_NODES + 3) / 4, 256, 0, stream>>>(rowptr, edge2, xm1s, dis, b1, W2, xm2s);
        // ---- gather2 + bias -> out fp32 ----
        k_gather_out<<<(N_NODES + 3) / 4, 256, 0, stream>>>(rowptr, edge2, xm2s, dis, b2, out);
    } else {
        // ---- fallback: atomic-scatter pipeline (ws >= ~33 MB) ----
        float* fdis  = (float*)d_ws;
        float* coef  = fdis + N_NODES;
        float* fxm   = coef + N_EDGES;
        float* fh    = fxm + (size_t)N_NODES * D;

        hipMemsetAsync(fdis, 0, N_NODES * sizeof(float), stream);
        k_hist<<<(N_EDGES + 255) / 256, 256, 0, stream>>>(dst, w, fdis);
        k_disf<<<(N_NODES + 255) / 256, 256, 0, stream>>>(fdis);
        k_coef<<<(N_EDGES + 255) / 256, 256, 0, stream>>>(src, dst, w, fdis, coef);

        k_gemm32f<<<(N_NODES + 7) / 8, 256, 0, stream>>>(x, W1, fxm);
        hipMemsetAsync(fh, 0, (size_t)N_NODES * D * sizeof(float), stream);
        k_scatter<<<(int)(((long long)N_EDGES * D + 255) / 256), 256, 0, stream>>>(src, dst, coef, fxm, fh);
        k_final<<<(N_NODES * D + 255) / 256, 256, 0, stream>>>(fh, fxm, fdis, b1, 1);

        k_gemm32f<<<(N_NODES + 7) / 8, 256, 0, stream>>>(fh, W2, fxm);
        hipMemsetAsync(out, 0, (size_t)out_size * sizeof(float), stream);
        k_scatter<<<(int)(((long long)N_EDGES * D + 255) / 256), 256, 0, stream>>>(src, dst, coef, fxm, out);
        k_final<<<(N_NODES * D + 255) / 256, 256, 0, stream>>>(out, fxm, fdis, b2, 0);
    }
}

// Round 8
// 133.910 us; speedup vs baseline: 3.7275x; 1.4126x over previous
//
#include <hip/hip_runtime.h>
#include <hip/hip_fp16.h>

#define N_NODES 100000
#define N_EDGES 1600000
#define D 32
#define EPB 4096                                   // edges per level-1 block
#define NBLK ((N_EDGES + EPB - 1) / EPB)           // 391 level-1 blocks
#define NBC ((N_NODES + 255) / 256)                // 391 coarse buckets (256 nodes each)
#define NBB (NBC * NBLK)                           // 152881 scan entries
#define SCAN_BLK 1024
#define SNB1 ((NBB + SCAN_BLK - 1) / SCAN_BLK)     // 150
#define WFX_SCALE 67108864.0f                      // 2^26 fixed point for deg

// --------------------------------------------------------------- level-1 count
__global__ void k_bcount(const int* __restrict__ dst, int* __restrict__ bhist) {
    __shared__ int hist[NBC];
    int t = threadIdx.x;
    for (int i = t; i < NBC; i += 1024) hist[i] = 0;
    __syncthreads();
    int base = blockIdx.x * EPB;
#pragma unroll
    for (int i = 0; i < 4; ++i) {
        int e = base + i * 1024 + t;
        if (e < N_EDGES) {
            int d = dst[e];
            if ((unsigned)d < N_NODES) atomicAdd(&hist[d >> 8], 1);
        }
    }
    __syncthreads();
    for (int c = t; c < NBC; c += 1024) bhist[c * NBLK + blockIdx.x] = hist[c];
}

// ----------------------------------------------------------------- scans (n)
__global__ void k_scan1(const int* __restrict__ in, int* __restrict__ incl,
                        int* __restrict__ bsum, int n) {
    __shared__ int sh[SCAN_BLK];
    int t = threadIdx.x;
    int g = blockIdx.x * SCAN_BLK + t;
    int v = (g < n) ? in[g] : 0;
    sh[t] = v;
    __syncthreads();
    for (int off = 1; off < SCAN_BLK; off <<= 1) {
        int add = (t >= off) ? sh[t - off] : 0;
        __syncthreads();
        sh[t] += add;
        __syncthreads();
    }
    if (g < n) incl[g] = sh[t];
    if (t == SCAN_BLK - 1) bsum[blockIdx.x] = sh[t];
}

__global__ void k_scan2(const int* __restrict__ bsum, int* __restrict__ boffs, int nb) {
    __shared__ int sh[256];
    int t = threadIdx.x;
    int v = (t < nb) ? bsum[t] : 0;
    sh[t] = v;
    __syncthreads();
    for (int off = 1; off < 256; off <<= 1) {
        int add = (t >= off) ? sh[t - off] : 0;
        __syncthreads();
        sh[t] += add;
        __syncthreads();
    }
    if (t < nb) boffs[t] = sh[t] - v;  // exclusive
}

__global__ void k_scan3(const int* __restrict__ in, const int* __restrict__ incl,
                        const int* __restrict__ boffs, int* __restrict__ outp, int n) {
    int g = blockIdx.x * 256 + threadIdx.x;
    if (g < n) outp[g] = incl[g] - in[g] + boffs[g / SCAN_BLK];
}

// -------------------------------------------------------------- level-1 scatter
__global__ void k_bscatter(const int* __restrict__ src, const int* __restrict__ dst,
                           const float* __restrict__ w, const int* __restrict__ sbase,
                           uint2* __restrict__ bucketed) {
    __shared__ int hist[NBC];
    __shared__ int lsb[NBC];
    int t = threadIdx.x;
    for (int i = t; i < NBC; i += 1024) {
        hist[i] = 0;
        lsb[i] = sbase[i * NBLK + blockIdx.x];
    }
    __syncthreads();
    int base = blockIdx.x * EPB;
#pragma unroll
    for (int i = 0; i < 4; ++i) {
        int e = base + i * 1024 + t;
        if (e < N_EDGES) {
            int d = dst[e];
            if ((unsigned)d < N_NODES) {
                int c = d >> 8;
                int r = atomicAdd(&hist[c], 1);
                uint2 rec;
                rec.x = ((unsigned)src[e] & 0xFFFFFu) | ((unsigned)(d & 255) << 20);
                rec.y = __float_as_uint(w[e]);
                bucketed[lsb[c] + r] = rec;
            }
        }
    }
}

// ----------------------------------------------------- level-2 CSR finalization
__global__ void k_build(const int* __restrict__ sbase, const uint2* __restrict__ bucketed,
                        int* __restrict__ rowptr, float* __restrict__ dis,
                        float2* __restrict__ edge2) {
    __shared__ int cnt[256], lb[256], fill[256], sh[256];
    __shared__ unsigned wfx[256];
    int t = threadIdx.x, c = blockIdx.x;
    cnt[t] = 0; fill[t] = 0; wfx[t] = 0;
    __syncthreads();
    int beg = sbase[c * NBLK];
    int end = (c == NBC - 1) ? N_EDGES : sbase[(c + 1) * NBLK];
    for (int i = beg + t; i < end; i += 256) {
        uint2 rec = bucketed[i];
        int dlow = rec.x >> 20;
        atomicAdd(&cnt[dlow], 1);
        atomicAdd(&wfx[dlow], (unsigned)(__uint_as_float(rec.y) * WFX_SCALE));
    }
    __syncthreads();
    int v = cnt[t];
    sh[t] = v;
    __syncthreads();
    for (int off = 1; off < 256; off <<= 1) {
        int add = (t >= off) ? sh[t - off] : 0;
        __syncthreads();
        sh[t] += add;
        __syncthreads();
    }
    int ex = sh[t] - v;
    lb[t] = ex;
    int node = c * 256 + t;
    if (node < N_NODES) {
        rowptr[node] = beg + ex;
        float deg = (float)wfx[t] * (1.0f / WFX_SCALE);
        dis[node] = rsqrtf(deg + 1.0f);
    }
    if (c == 0 && t == 0) rowptr[N_NODES] = N_EDGES;
    __syncthreads();
    for (int i = beg + t; i < end; i += 256) {
        uint2 rec = bucketed[i];
        int dlow = rec.x >> 20;
        int r = atomicAdd(&fill[dlow], 1);
        float2 e2;
        e2.x = __uint_as_float(rec.y);                       // w
        e2.y = __int_as_float((int)(rec.x & 0xFFFFFu));      // src
        edge2[beg + lb[dlow] + r] = e2;
    }
}

// ---------------------------------------------------------------- GEMM (fp16 out)
// Y[n][j] = dis[n] * sum_k X[n][k] * W[k][j], stored half (dis pre-folded)
__global__ void k_gemm32h(const float* __restrict__ X, const float* __restrict__ W,
                          const float* __restrict__ dis, __half* __restrict__ Y) {
    __shared__ float Ws[D * D];
    __shared__ float Xs[8][D];
    int t = threadIdx.x;
    for (int i = t; i < D * D; i += 256) Ws[i] = W[i];
    int local = t >> 5, j = t & 31;
    int node = blockIdx.x * 8 + local;
    if (node < N_NODES) Xs[local][j] = X[node * D + j];
    __syncthreads();
    if (node < N_NODES) {
        float acc = 0.f;
#pragma unroll
        for (int k = 0; k < D; ++k) acc = fmaf(Xs[local][k], Ws[k * D + j], acc);
        Y[(size_t)node * D + j] = __float2half(acc * dis[node]);
    }
}

// ------------------------------------------------------------- gather + fused W2
// 16-lane group per node; lane g owns features {2g, 2g+1} via __half2 loads.
// 4 nodes per wave -> 16 independent edge chains per wave (latency hiding).
// h[f] = relu( dis*( sum_e w*xms[src][f] + xms[n][f] ) + b1[f] )
// y[j] = dis * sum_f h[f]*W2[f][j], stored fp16 (h enters product fp16-rounded)
__global__ void k_gather_mid(const int* __restrict__ rowptr, const float2* __restrict__ edge2,
                             const __half* __restrict__ xm, const float* __restrict__ dis,
                             const float* __restrict__ b, const float* __restrict__ W2,
                             __half* __restrict__ y) {
    __shared__ float2 W2p[D][16];   // W2p[f][g] = (W2[f][2g], W2[f][2g+1])
    int t = threadIdx.x;
    for (int i = t; i < D * 16; i += 256) {
        int f = i >> 4, g = i & 15;
        W2p[f][g] = make_float2(W2[f * D + 2 * g], W2[f * D + 2 * g + 1]);
    }
    __syncthreads();
    int node = blockIdx.x * 16 + (t >> 4);
    if (node >= N_NODES) return;
    int g = t & 15;
    int beg = rowptr[node], end = rowptr[node + 1];
    float a00 = 0.f, a01 = 0.f, a10 = 0.f, a11 = 0.f;
    float a20 = 0.f, a21 = 0.f, a30 = 0.f, a31 = 0.f;
    int j = beg;
    for (; j + 3 < end; j += 4) {
        float2 e0 = edge2[j],     e1 = edge2[j + 1];
        float2 e2 = edge2[j + 2], e3 = edge2[j + 3];
        float2 x0 = __half22float2(*(const __half2*)(xm + (size_t)__float_as_int(e0.y) * D + 2 * g));
        float2 x1 = __half22float2(*(const __half2*)(xm + (size_t)__float_as_int(e1.y) * D + 2 * g));
        float2 x2 = __half22float2(*(const __half2*)(xm + (size_t)__float_as_int(e2.y) * D + 2 * g));
        float2 x3 = __half22float2(*(const __half2*)(xm + (size_t)__float_as_int(e3.y) * D + 2 * g));
        a00 = fmaf(e0.x, x0.x, a00); a01 = fmaf(e0.x, x0.y, a01);
        a10 = fmaf(e1.x, x1.x, a10); a11 = fmaf(e1.x, x1.y, a11);
        a20 = fmaf(e2.x, x2.x, a20); a21 = fmaf(e2.x, x2.y, a21);
        a30 = fmaf(e3.x, x3.x, a30); a31 = fmaf(e3.x, x3.y, a31);
    }
    for (; j < end; ++j) {
        float2 e0 = edge2[j];
        float2 x0 = __half22float2(*(const __half2*)(xm + (size_t)__float_as_int(e0.y) * D + 2 * g));
        a00 = fmaf(e0.x, x0.x, a00); a01 = fmaf(e0.x, x0.y, a01);
    }
    float s = dis[node];
    float2 self = __half22float2(*(const __half2*)(xm + (size_t)node * D + 2 * g));
    float h0 = fmaxf(s * ((a00 + a10) + (a20 + a30) + self.x) + b[2 * g], 0.f);
    float h1 = fmaxf(s * ((a01 + a11) + (a21 + a31) + self.y) + b[2 * g + 1], 0.f);
    // pack h pair to fp16 and broadcast within the 16-lane group
    __half2 hp = __floats2half2_rn(h0, h1);
    float hpf = __uint_as_float(*(unsigned*)&hp);
    float acc0 = 0.f, acc1 = 0.f;
#pragma unroll
    for (int k = 0; k < 16; ++k) {
        float r = __shfl(hpf, k, 16);
        unsigned u = __float_as_uint(r);
        float2 hh = __half22float2(*(__half2*)&u);
        float2 wa = W2p[2 * k][g];
        float2 wb = W2p[2 * k + 1][g];
        acc0 = fmaf(hh.x, wa.x, acc0); acc1 = fmaf(hh.x, wa.y, acc1);
        acc0 = fmaf(hh.y, wb.x, acc0); acc1 = fmaf(hh.y, wb.y, acc1);
    }
    *(__half2*)(y + (size_t)node * D + 2 * g) = __floats2half2_rn(s * acc0, s * acc1);
}

// ------------------------------------------------------------------ final gather
// out[n][f] = dis[n]*( sum_e w_e*xms[src_e][f] + xms[n][f] ) + b2[f]
__global__ void k_gather_out(const int* __restrict__ rowptr, const float2* __restrict__ edge2,
                             const __half* __restrict__ xm, const float* __restrict__ dis,
                             const float* __restrict__ b, float* __restrict__ out) {
    int t = threadIdx.x;
    int node = blockIdx.x * 16 + (t >> 4);
    if (node >= N_NODES) return;
    int g = t & 15;
    int beg = rowptr[node], end = rowptr[node + 1];
    float a00 = 0.f, a01 = 0.f, a10 = 0.f, a11 = 0.f;
    float a20 = 0.f, a21 = 0.f, a30 = 0.f, a31 = 0.f;
    int j = beg;
    for (; j + 3 < end; j += 4) {
        float2 e0 = edge2[j],     e1 = edge2[j + 1];
        float2 e2 = edge2[j + 2], e3 = edge2[j + 3];
        float2 x0 = __half22float2(*(const __half2*)(xm + (size_t)__float_as_int(e0.y) * D + 2 * g));
        float2 x1 = __half22float2(*(const __half2*)(xm + (size_t)__float_as_int(e1.y) * D + 2 * g));
        float2 x2 = __half22float2(*(const __half2*)(xm + (size_t)__float_as_int(e2.y) * D + 2 * g));
        float2 x3 = __half22float2(*(const __half2*)(xm + (size_t)__float_as_int(e3.y) * D + 2 * g));
        a00 = fmaf(e0.x, x0.x, a00); a01 = fmaf(e0.x, x0.y, a01);
        a10 = fmaf(e1.x, x1.x, a10); a11 = fmaf(e1.x, x1.y, a11);
        a20 = fmaf(e2.x, x2.x, a20); a21 = fmaf(e2.x, x2.y, a21);
        a30 = fmaf(e3.x, x3.x, a30); a31 = fmaf(e3.x, x3.y, a31);
    }
    for (; j < end; ++j) {
        float2 e0 = edge2[j];
        float2 x0 = __half22float2(*(const __half2*)(xm + (size_t)__float_as_int(e0.y) * D + 2 * g));
        a00 = fmaf(e0.x, x0.x, a00); a01 = fmaf(e0.x, x0.y, a01);
    }
    float s = dis[node];
    float2 self = __half22float2(*(const __half2*)(xm + (size_t)node * D + 2 * g));
    float o0 = s * ((a00 + a10) + (a20 + a30) + self.x) + b[2 * g];
    float o1 = s * ((a01 + a11) + (a21 + a31) + self.y) + b[2 * g + 1];
    *(float2*)(out + (size_t)node * D + 2 * g) = make_float2(o0, o1);
}

// ------------------------------------------------- fallback (atomic pipeline)
__global__ void k_hist(const int* __restrict__ dst, const float* __restrict__ w,
                       float* __restrict__ deg) {
    int e = blockIdx.x * blockDim.x + threadIdx.x;
    if (e < N_EDGES) {
        int d = dst[e];
        if ((unsigned)d < N_NODES) atomicAdd(&deg[d], w[e]);
    }
}

__global__ void k_disf(float* __restrict__ deg) {
    int i = blockIdx.x * blockDim.x + threadIdx.x;
    if (i < N_NODES) deg[i] = rsqrtf(deg[i] + 1.0f);
}

__global__ void k_coef(const int* __restrict__ src, const int* __restrict__ dst,
                       const float* __restrict__ w, const float* __restrict__ dis,
                       float* __restrict__ coef) {
    int e = blockIdx.x * blockDim.x + threadIdx.x;
    if (e < N_EDGES) {
        int s = src[e], d = dst[e];
        float c = 0.f;
        if ((unsigned)s < N_NODES && (unsigned)d < N_NODES)
            c = dis[s] * w[e] * dis[d];
        coef[e] = c;
    }
}

__global__ void k_gemm32f(const float* __restrict__ X, const float* __restrict__ W,
                          float* __restrict__ Y) {
    __shared__ float Ws[D * D];
    __shared__ float Xs[8][D];
    int t = threadIdx.x;
    for (int i = t; i < D * D; i += 256) Ws[i] = W[i];
    int local = t >> 5, j = t & 31;
    int node = blockIdx.x * 8 + local;
    if (node < N_NODES) Xs[local][j] = X[node * D + j];
    __syncthreads();
    if (node < N_NODES) {
        float acc = 0.f;
#pragma unroll
        for (int k = 0; k < D; ++k) acc = fmaf(Xs[local][k], Ws[k * D + j], acc);
        Y[node * D + j] = acc;
    }
}

__global__ void k_scatter(const int* __restrict__ src, const int* __restrict__ dst,
                          const float* __restrict__ coef, const float* __restrict__ xm,
                          float* __restrict__ out) {
    long long gid = (long long)blockIdx.x * blockDim.x + threadIdx.x;
    if (gid >= (long long)N_EDGES * D) return;
    int e = (int)(gid >> 5);
    int f = (int)(gid & 31);
    int s = src[e], d = dst[e];
    if ((unsigned)s >= N_NODES || (unsigned)d >= N_NODES) return;
    atomicAdd(&out[d * D + f], coef[e] * xm[s * D + f]);
}

__global__ void k_final(float* __restrict__ acc, const float* __restrict__ xm,
                        const float* __restrict__ dis, const float* __restrict__ b,
                        int do_relu) {
    int gid = blockIdx.x * blockDim.x + threadIdx.x;
    if (gid < N_NODES * D) {
        int i = gid >> 5, f = gid & 31;
        float s = dis[i];
        float v = acc[gid] + s * s * xm[gid] + b[f];
        if (do_relu) v = fmaxf(v, 0.f);
        acc[gid] = v;
    }
}

extern "C" void kernel_launch(void* const* d_in, const int* in_sizes, int n_in,
                              void* d_out, int out_size, void* d_ws, size_t ws_size,
                              hipStream_t stream) {
    const float* x  = (const float*)d_in[0];
    const int*   ei = (const int*)d_in[1];   // [2, E] flat: row 0 = src, row 1 = dst
    const float* w  = (const float*)d_in[2];
    const float* W1 = (const float*)d_in[3];
    const float* b1 = (const float*)d_in[4];
    const float* W2 = (const float*)d_in[5];
    const float* b2 = (const float*)d_in[6];
    const int* src = ei;
    const int* dst = ei + N_EDGES;
    float* out = (float*)d_out;

    // ---- workspace layout (~27.5 MB) ----
    char* p = (char*)d_ws;
    uint2*  bucketed = (uint2*)p;   p += (size_t)N_EDGES * 8;
    float2* edge2    = (float2*)p;  p += (size_t)N_EDGES * 8;
    int*    bhist    = (int*)p;     p += (size_t)NBB * 4 + 4;
    int*    incl     = (int*)p;     p += (size_t)NBB * 4 + 4;
    int*    sbase    = (int*)p;     p += (size_t)NBB * 4 + 4;
    int*    bsum     = (int*)p;     p += 1024;
    int*    boffs    = (int*)p;     p += 1024;
    size_t need = (size_t)(p - (char*)d_ws);

    __half* xm1s  = (__half*)bucketed;                          // 6.4 MB
    __half* xm2s  = (__half*)bucketed + (size_t)N_NODES * D;    // next 6.4 MB
    int*    rowptr = incl;             // live after k_scan3 consumed incl
    float*  dis    = (float*)bhist;    // live after k_scan3 consumed bhist

    if (ws_size >= need) {
        // ---- CSR build: zero global atomics; dis folded into k_build ----
        k_bcount<<<NBLK, 1024, 0, stream>>>(dst, bhist);
        k_scan1<<<SNB1, SCAN_BLK, 0, stream>>>(bhist, incl, bsum, NBB);
        k_scan2<<<1, 256, 0, stream>>>(bsum, boffs, SNB1);
        k_scan3<<<(NBB + 255) / 256, 256, 0, stream>>>(bhist, incl, boffs, sbase, NBB);
        k_bscatter<<<NBLK, 1024, 0, stream>>>(src, dst, w, sbase, bucketed);
        k_build<<<NBC, 256, 0, stream>>>(sbase, bucketed, rowptr, dis, edge2);

        // ---- layer 1 GEMM: xm1s = dis * (x @ W1), fp16 ----
        k_gemm32h<<<(N_NODES + 7) / 8, 256, 0, stream>>>(x, W1, dis, xm1s);
        // ---- gather1 + bias/relu + fused @W2 + dis-scale -> xm2s fp16 ----
        k_gather_mid<<<(N_NODES + 15) / 16, 256, 0, stream>>>(rowptr, edge2, xm1s, dis, b1, W2, xm2s);
        // ---- gather2 + bias -> out fp32 ----
        k_gather_out<<<(N_NODES + 15) / 16, 256, 0, stream>>>(rowptr, edge2, xm2s, dis, b2, out);
    } else {
        // ---- fallback: atomic-scatter pipeline (ws >= ~33 MB) ----
        float* fdis  = (float*)d_ws;
        float* coef  = fdis + N_NODES;
        float* fxm   = coef + N_EDGES;
        float* fh    = fxm + (size_t)N_NODES * D;

        hipMemsetAsync(fdis, 0, N_NODES * sizeof(float), stream);
        k_hist<<<(N_EDGES + 255) / 256, 256, 0, stream>>>(dst, w, fdis);
        k_disf<<<(N_NODES + 255) / 256, 256, 0, stream>>>(fdis);
        k_coef<<<(N_EDGES + 255) / 256, 256, 0, stream>>>(src, dst, w, fdis, coef);

        k_gemm32f<<<(N_NODES + 7) / 8, 256, 0, stream>>>(x, W1, fxm);
        hipMemsetAsync(fh, 0, (size_t)N_NODES * D * sizeof(float), stream);
        k_scatter<<<(int)(((long long)N_EDGES * D + 255) / 256), 256, 0, stream>>>(src, dst, coef, fxm, fh);
        k_final<<<(N_NODES * D + 255) / 256, 256, 0, stream>>>(fh, fxm, fdis, b1, 1);

        k_gemm32f<<<(N_NODES + 7) / 8, 256, 0, stream>>>(fh, W2, fxm);
        hipMemsetAsync(out, 0, (size_t)out_size * sizeof(float), stream);
        k_scatter<<<(int)(((long long)N_EDGES * D + 255) / 256), 256, 0, stream>>>(src, dst, coef, fxm, out);
        k_final<<<(N_NODES * D + 255) / 256, 256, 0, stream>>>(out, fxm, fdis, b2, 0);
    }
}